// Round 1
// baseline (5651.611 us; speedup 1.0000x reference)
//
#include <hip/hip_runtime.h>

#define NN 100000
#define NE 1600000
#define FD 128

// ---------------- degree / norm precompute ----------------

__global__ void k_deg_init(float* __restrict__ deg) {
    int i = blockIdx.x * 256 + threadIdx.x;
    if (i < NN) deg[i] = 1.0f;   // self-loop contribution
}

__global__ void k_deg_count(const int* __restrict__ col, float* __restrict__ deg) {
    int e = blockIdx.x * 256 + threadIdx.x;
    if (e < NE) {
        int c = col[e];
        if ((unsigned)c < NN) unsafeAtomicAdd(&deg[c], 1.0f);
    }
}

__global__ void k_dis(const float* __restrict__ deg, float* __restrict__ dis) {
    int i = blockIdx.x * 256 + threadIdx.x;
    if (i < NN) dis[i] = rsqrtf(deg[i]);
}

// ---------------- dense GEMM: out[r][f] = sum_k act(in[r][k]) * W[k][f] ----------------
// W (128x128 f32 = 64KB) staged in LDS once per block; 8 rows per block-iter,
// each thread computes a float4 of output features for one row.

template <bool RELU>
__global__ __launch_bounds__(256, 2) void k_gemm(const float* __restrict__ in,
                                                 const float* __restrict__ W,
                                                 float* __restrict__ out) {
    __shared__ float Ws[FD * FD];   // 64 KB
    __shared__ float xs[8][FD];     // 4 KB

    const int tid = threadIdx.x;

    // cooperative W load (4096 float4 / 256 threads = 16 each)
    {
        const float4* W4 = (const float4*)W;
        float4* Ws4 = (float4*)Ws;
#pragma unroll
        for (int i = 0; i < 16; ++i) Ws4[tid + 256 * i] = W4[tid + 256 * i];
    }

    const int rl = tid >> 5;        // row within 8-row group
    const int f4 = tid & 31;        // float4 column index

    for (int g = blockIdx.x; g < NN / 8; g += gridDim.x) {
        const int row0 = g * 8;
        __syncthreads();            // protect xs against previous iter readers
        // load 8 rows of x (256 float4)
        {
            const float4* in4 = (const float4*)(in + (size_t)row0 * FD);
            float4 v = in4[tid];
            if (RELU) {
                v.x = fmaxf(v.x, 0.0f); v.y = fmaxf(v.y, 0.0f);
                v.z = fmaxf(v.z, 0.0f); v.w = fmaxf(v.w, 0.0f);
            }
            ((float4*)xs)[tid] = v;
        }
        __syncthreads();

        float4 acc = {0.0f, 0.0f, 0.0f, 0.0f};
        const float4* WsR = (const float4*)Ws;
#pragma unroll 8
        for (int k = 0; k < FD; ++k) {
            const float xv = xs[rl][k];
            const float4 wv = WsR[k * 32 + f4];
            acc.x += xv * wv.x; acc.y += xv * wv.y;
            acc.z += xv * wv.z; acc.w += xv * wv.w;
        }
        ((float4*)(out + (size_t)(row0 + rl) * FD))[f4] = acc;
    }
}

// ---------------- aggregation ----------------
// init: out[v][f] = b[f] + (1/deg[v]) * h[v][f]   (self-loop, norm = dis[v]^2)
__global__ __launch_bounds__(256) void k_agg_init(const float* __restrict__ h,
                                                  const float* __restrict__ b,
                                                  const float* __restrict__ dis,
                                                  float* __restrict__ out) {
    int i4 = blockIdx.x * 256 + threadIdx.x;       // float4 index
    if (i4 >= NN * FD / 4) return;
    int v = i4 >> 5;            // 32 float4 per node
    int f4 = i4 & 31;
    float d = dis[v];
    float sl = d * d;
    float4 hv = ((const float4*)h)[i4];
    const float4 bv = ((const float4*)b)[f4];
    float4 o;
    o.x = bv.x + sl * hv.x; o.y = bv.y + sl * hv.y;
    o.z = bv.z + sl * hv.z; o.w = bv.w + sl * hv.w;
    ((float4*)out)[i4] = o;
}

// edges: out[col][f] += dis[row]*dis[col] * h[row][f]
// 8 edges per 256-thread block; 32 threads per edge, float4 per thread.
__global__ __launch_bounds__(256) void k_agg_edges(const int* __restrict__ row,
                                                   const int* __restrict__ col,
                                                   const float* __restrict__ dis,
                                                   const float* __restrict__ h,
                                                   float* __restrict__ out) {
    const int e = blockIdx.x * 8 + (threadIdx.x >> 5);
    const int f4 = threadIdx.x & 31;
    if (e >= NE) return;
    const int r = row[e];
    const int c = col[e];
    if ((unsigned)r >= NN || (unsigned)c >= NN) return;
    const float ne = dis[r] * dis[c];
    const float4 hv = ((const float4*)(h + (size_t)r * FD))[f4];
    float* op = out + (size_t)c * FD + f4 * 4;
    unsafeAtomicAdd(op + 0, ne * hv.x);
    unsafeAtomicAdd(op + 1, ne * hv.y);
    unsafeAtomicAdd(op + 2, ne * hv.z);
    unsafeAtomicAdd(op + 3, ne * hv.w);
}

// ---------------- launch ----------------

extern "C" void kernel_launch(void* const* d_in, const int* in_sizes, int n_in,
                              void* d_out, int out_size, void* d_ws, size_t ws_size,
                              hipStream_t stream) {
    const float* x  = (const float*)d_in[0];
    const int*   ei = (const int*)d_in[1];     // [2][NE] int32
    const float* W1 = (const float*)d_in[2];
    const float* b1 = (const float*)d_in[3];
    const float* W2 = (const float*)d_in[4];
    const float* b2 = (const float*)d_in[5];
    float* out = (float*)d_out;

    float* ws  = (float*)d_ws;
    float* deg = ws;                    // NN
    float* dis = ws + NN;               // NN
    float* h   = ws + 2 * NN;           // NN*FD
    float* agg = h + (size_t)NN * FD;   // NN*FD

    const int* row = ei;        // edge_index[0] = source (gather side)
    const int* col = ei + NE;   // edge_index[1] = target (scatter side)

    // graph norm (shared by both layers)
    k_deg_init<<<(NN + 255) / 256, 256, 0, stream>>>(deg);
    k_deg_count<<<(NE + 255) / 256, 256, 0, stream>>>(col, deg);
    k_dis<<<(NN + 255) / 256, 256, 0, stream>>>(deg, dis);

    // layer 1
    k_gemm<false><<<2048, 256, 0, stream>>>(x, W1, h);
    k_agg_init<<<NN * FD / 4 / 256, 256, 0, stream>>>(h, b1, dis, agg);
    k_agg_edges<<<NE / 8, 256, 0, stream>>>(row, col, dis, h, agg);

    // layer 2 (ReLU fused into GEMM input load); write final into d_out
    k_gemm<true><<<2048, 256, 0, stream>>>(agg, W2, h);
    k_agg_init<<<NN * FD / 4 / 256, 256, 0, stream>>>(h, b2, dis, out);
    k_agg_edges<<<NE / 8, 256, 0, stream>>>(row, col, dis, h, out);
}

// Round 2
// 627.173 us; speedup vs baseline: 9.0112x; 9.0112x over previous
//
#include <hip/hip_runtime.h>

#define NN 100000
#define NE 1600000
#define FD 128
#define SCAN_BLOCKS 98   // ceil(NN / 1024)

// ================= graph build (CSC by destination) =================

__global__ void k_zero(int* __restrict__ p, int n) {
    int i = blockIdx.x * 256 + threadIdx.x;
    if (i < n) p[i] = 0;
}

__global__ void k_count(const int* __restrict__ col, int* __restrict__ cnt) {
    int e = blockIdx.x * 256 + threadIdx.x;
    if (e < NE) {
        int c = col[e];
        if ((unsigned)c < NN) atomicAdd(&cnt[c], 1);
    }
}

// block-local exclusive scan over 1024 elems (256 thr x 4); bsums[b] = block total
__global__ void k_scan1(const int* __restrict__ cnt, int* __restrict__ row_ptr,
                        int* __restrict__ bsums) {
    __shared__ int s[256];
    const int tid = threadIdx.x;
    const int base = blockIdx.x * 1024 + tid * 4;
    int v0 = 0, v1 = 0, v2 = 0, v3 = 0;
    if (base + 0 < NN) v0 = cnt[base + 0];
    if (base + 1 < NN) v1 = cnt[base + 1];
    if (base + 2 < NN) v2 = cnt[base + 2];
    if (base + 3 < NN) v3 = cnt[base + 3];
    s[tid] = v0 + v1 + v2 + v3;
    __syncthreads();
    for (int off = 1; off < 256; off <<= 1) {
        int t = 0;
        if (tid >= off) t = s[tid - off];
        __syncthreads();
        if (tid >= off) s[tid] += t;
        __syncthreads();
    }
    int excl = (tid == 0) ? 0 : s[tid - 1];
    if (base + 0 < NN) row_ptr[base + 0] = excl;
    if (base + 1 < NN) row_ptr[base + 1] = excl + v0;
    if (base + 2 < NN) row_ptr[base + 2] = excl + v0 + v1;
    if (base + 3 < NN) row_ptr[base + 3] = excl + v0 + v1 + v2;
    if (tid == 255) bsums[blockIdx.x] = s[255];
}

__global__ void k_scan2(int* __restrict__ bsums, int nb, int* __restrict__ row_ptr) {
    if (threadIdx.x == 0 && blockIdx.x == 0) {
        int acc = 0;
        for (int i = 0; i < nb; ++i) { int t = bsums[i]; bsums[i] = acc; acc += t; }
        row_ptr[NN] = acc;
    }
}

// row_ptr += block offset; cursor = row_ptr; dis = rsqrt(deg_in + 1 self-loop)
__global__ void k_finalize(const int* __restrict__ cnt, const int* __restrict__ bsums,
                           int* __restrict__ row_ptr, int* __restrict__ cursor,
                           float* __restrict__ dis) {
    int i = blockIdx.x * 256 + threadIdx.x;
    if (i < NN) {
        int rp = row_ptr[i] + bsums[i >> 10];
        row_ptr[i] = rp;
        cursor[i] = rp;
        dis[i] = rsqrtf((float)cnt[i] + 1.0f);
    }
}

__global__ void k_scatter(const int* __restrict__ row, const int* __restrict__ col,
                          int* __restrict__ cursor, int* __restrict__ srcs) {
    int e = blockIdx.x * 256 + threadIdx.x;
    if (e < NE) {
        int c = col[e];
        if ((unsigned)c < NN) {
            int pos = atomicAdd(&cursor[c], 1);
            srcs[pos] = row[e];
        }
    }
}

// ================= dense GEMM: out[r][f] = sum_k act(in[r][k]) * W[k][f] =======

template <bool RELU>
__global__ __launch_bounds__(256, 2) void k_gemm(const float* __restrict__ in,
                                                 const float* __restrict__ W,
                                                 float* __restrict__ out) {
    __shared__ float Ws[FD * FD];   // 64 KB
    __shared__ float xs[8][FD];     // 4 KB

    const int tid = threadIdx.x;
    {
        const float4* W4 = (const float4*)W;
        float4* Ws4 = (float4*)Ws;
#pragma unroll
        for (int i = 0; i < 16; ++i) Ws4[tid + 256 * i] = W4[tid + 256 * i];
    }

    const int rl = tid >> 5;
    const int f4 = tid & 31;

    for (int g = blockIdx.x; g < NN / 8; g += gridDim.x) {
        const int row0 = g * 8;
        __syncthreads();
        {
            const float4* in4 = (const float4*)(in + (size_t)row0 * FD);
            float4 v = in4[tid];
            if (RELU) {
                v.x = fmaxf(v.x, 0.0f); v.y = fmaxf(v.y, 0.0f);
                v.z = fmaxf(v.z, 0.0f); v.w = fmaxf(v.w, 0.0f);
            }
            ((float4*)xs)[tid] = v;
        }
        __syncthreads();

        float4 acc = {0.0f, 0.0f, 0.0f, 0.0f};
        const float4* WsR = (const float4*)Ws;
#pragma unroll 8
        for (int k = 0; k < FD; ++k) {
            const float xv = xs[rl][k];
            const float4 wv = WsR[k * 32 + f4];
            acc.x += xv * wv.x; acc.y += xv * wv.y;
            acc.z += xv * wv.z; acc.w += xv * wv.w;
        }
        ((float4*)(out + (size_t)(row0 + rl) * FD))[f4] = acc;
    }
}

// ================= aggregation by gather =================
// out[v] = b + dis[v]^2 * h[v] + sum_{e in CSC[v]} dis[v]*dis[src] * h[src]
__global__ __launch_bounds__(256) void k_agg_gather(const float* __restrict__ h,
                                                    const float* __restrict__ b,
                                                    const float* __restrict__ dis,
                                                    const int* __restrict__ row_ptr,
                                                    const int* __restrict__ srcs,
                                                    float* __restrict__ out) {
    const int v = (blockIdx.x * 256 + threadIdx.x) >> 5;
    if (v >= NN) return;
    const int f4 = threadIdx.x & 31;
    const float4* h4 = (const float4*)h;

    const float dv = dis[v];
    float4 acc = ((const float4*)b)[f4];
    {
        const float sl = dv * dv;
        float4 hv = h4[(size_t)v * 32 + f4];
        acc.x += sl * hv.x; acc.y += sl * hv.y;
        acc.z += sl * hv.z; acc.w += sl * hv.w;
    }

    int e = row_ptr[v];
    const int end = row_ptr[v + 1];
    for (; e + 1 < end; e += 2) {
        const int s0 = srcs[e], s1 = srcs[e + 1];
        const float w0 = dv * dis[s0];
        const float w1 = dv * dis[s1];
        const float4 a0 = h4[(size_t)s0 * 32 + f4];
        const float4 a1 = h4[(size_t)s1 * 32 + f4];
        acc.x += w0 * a0.x + w1 * a1.x;
        acc.y += w0 * a0.y + w1 * a1.y;
        acc.z += w0 * a0.z + w1 * a1.z;
        acc.w += w0 * a0.w + w1 * a1.w;
    }
    if (e < end) {
        const int s0 = srcs[e];
        const float w0 = dv * dis[s0];
        const float4 a0 = h4[(size_t)s0 * 32 + f4];
        acc.x += w0 * a0.x; acc.y += w0 * a0.y;
        acc.z += w0 * a0.z; acc.w += w0 * a0.w;
    }
    ((float4*)out)[(size_t)v * 32 + f4] = acc;
}

// ================= fallback (atomic scatter) kernels, R1 path =================

__global__ void fb_deg_init(float* __restrict__ deg) {
    int i = blockIdx.x * 256 + threadIdx.x;
    if (i < NN) deg[i] = 1.0f;
}
__global__ void fb_deg_count(const int* __restrict__ col, float* __restrict__ deg) {
    int e = blockIdx.x * 256 + threadIdx.x;
    if (e < NE) { int c = col[e]; if ((unsigned)c < NN) unsafeAtomicAdd(&deg[c], 1.0f); }
}
__global__ void fb_dis(const float* __restrict__ deg, float* __restrict__ dis) {
    int i = blockIdx.x * 256 + threadIdx.x;
    if (i < NN) dis[i] = rsqrtf(deg[i]);
}
__global__ __launch_bounds__(256) void fb_agg_init(const float* __restrict__ h,
                                                   const float* __restrict__ b,
                                                   const float* __restrict__ dis,
                                                   float* __restrict__ out) {
    int i4 = blockIdx.x * 256 + threadIdx.x;
    if (i4 >= NN * FD / 4) return;
    int v = i4 >> 5, f4 = i4 & 31;
    float d = dis[v], sl = d * d;
    float4 hv = ((const float4*)h)[i4];
    const float4 bv = ((const float4*)b)[f4];
    float4 o = {bv.x + sl * hv.x, bv.y + sl * hv.y, bv.z + sl * hv.z, bv.w + sl * hv.w};
    ((float4*)out)[i4] = o;
}
__global__ __launch_bounds__(256) void fb_agg_edges(const int* __restrict__ row,
                                                    const int* __restrict__ col,
                                                    const float* __restrict__ dis,
                                                    const float* __restrict__ h,
                                                    float* __restrict__ out) {
    const int e = blockIdx.x * 8 + (threadIdx.x >> 5);
    const int f4 = threadIdx.x & 31;
    if (e >= NE) return;
    const int r = row[e], c = col[e];
    if ((unsigned)r >= NN || (unsigned)c >= NN) return;
    const float ne = dis[r] * dis[c];
    const float4 hv = ((const float4*)(h + (size_t)r * FD))[f4];
    float* op = out + (size_t)c * FD + f4 * 4;
    unsafeAtomicAdd(op + 0, ne * hv.x);
    unsafeAtomicAdd(op + 1, ne * hv.y);
    unsafeAtomicAdd(op + 2, ne * hv.z);
    unsafeAtomicAdd(op + 3, ne * hv.w);
}

// ================= launch =================

extern "C" void kernel_launch(void* const* d_in, const int* in_sizes, int n_in,
                              void* d_out, int out_size, void* d_ws, size_t ws_size,
                              hipStream_t stream) {
    const float* x  = (const float*)d_in[0];
    const int*   ei = (const int*)d_in[1];
    const float* W1 = (const float*)d_in[2];
    const float* b1 = (const float*)d_in[3];
    const float* W2 = (const float*)d_in[4];
    const float* b2 = (const float*)d_in[5];
    float* out = (float*)d_out;

    const int* row = ei;        // source (gather side)
    const int* col = ei + NE;   // target (scatter side)

    // ---- workspace layout (16B-aligned big buffers) ----
    // ints: cnt[NN] | row_ptr[NN+32] | cursor[NN] | bsums[128]  => 4*NN+160 elems
    // then: dis[NN] f32 | h[NN*FD] | agg[NN*FD] | srcs[NE] int
    int*   cnt     = (int*)d_ws;
    int*   row_ptr = cnt + NN;
    int*   cursor  = row_ptr + NN + 32;
    int*   bsums   = cursor + NN;
    float* dis     = (float*)(bsums + 128);
    float* h       = dis + NN;
    float* agg     = h + (size_t)NN * FD;
    int*   srcs    = (int*)(agg + (size_t)NN * FD);
    const size_t NEED = ((size_t)(4 * NN + 160) + NN) * 4 + 2 * (size_t)NN * FD * 4
                        + (size_t)NE * 4;

    if (ws_size >= NEED) {
        // ---- CSC build (shared by both layers) ----
        k_zero<<<(NN + 255) / 256, 256, 0, stream>>>(cnt, NN);
        k_count<<<NE / 256, 256, 0, stream>>>(col, cnt);
        k_scan1<<<SCAN_BLOCKS, 256, 0, stream>>>(cnt, row_ptr, bsums);
        k_scan2<<<1, 64, 0, stream>>>(bsums, SCAN_BLOCKS, row_ptr);
        k_finalize<<<(NN + 255) / 256, 256, 0, stream>>>(cnt, bsums, row_ptr, cursor, dis);
        k_scatter<<<NE / 256, 256, 0, stream>>>(row, col, cursor, srcs);

        // ---- layer 1 ----
        k_gemm<false><<<2048, 256, 0, stream>>>(x, W1, h);
        k_agg_gather<<<NN * 32 / 256, 256, 0, stream>>>(h, b1, dis, row_ptr, srcs, agg);
        // ---- layer 2 ----
        k_gemm<true><<<2048, 256, 0, stream>>>(agg, W2, h);
        k_agg_gather<<<NN * 32 / 256, 256, 0, stream>>>(h, b2, dis, row_ptr, srcs, out);
    } else {
        // fallback: R1 atomic path (fits in 103.2 MB)
        float* fdeg = (float*)d_ws;
        float* fdis = fdeg + NN;
        float* fh   = fdis + NN;
        float* fagg = fh + (size_t)NN * FD;
        fb_deg_init<<<(NN + 255) / 256, 256, 0, stream>>>(fdeg);
        fb_deg_count<<<(NE + 255) / 256, 256, 0, stream>>>(col, fdeg);
        fb_dis<<<(NN + 255) / 256, 256, 0, stream>>>(fdeg, fdis);
        k_gemm<false><<<2048, 256, 0, stream>>>(x, W1, fh);
        fb_agg_init<<<NN * FD / 4 / 256, 256, 0, stream>>>(fh, b1, fdis, fagg);
        fb_agg_edges<<<NE / 8, 256, 0, stream>>>(row, col, fdis, fh, fagg);
        k_gemm<true><<<2048, 256, 0, stream>>>(fagg, W2, fh);
        fb_agg_init<<<NN * FD / 4 / 256, 256, 0, stream>>>(fh, b2, fdis, out);
        fb_agg_edges<<<NE / 8, 256, 0, stream>>>(row, col, fdis, fh, out);
    }
}

// Round 3
// 554.219 us; speedup vs baseline: 10.1974x; 1.1316x over previous
//
#include <hip/hip_runtime.h>

#define NN 100000
#define NE 1600000
#define FD 128
#define SCAN_BLOCKS 98      // ceil(NN / 1024)
#define NBUK 196            // ceil(NN / 512), bucket = col >> 9
#define EPB 4096            // edges per block in edge-pass kernels
#define NB_E 391            // ceil(NE / EPB)

// ================= graph build (CSC by destination, bucketed) =================

__global__ void k_zero(int* __restrict__ p, int n) {
    int i = blockIdx.x * 256 + threadIdx.x;
    if (i < n) p[i] = 0;
}

// fused: per-node degree count + per-bucket histogram
__global__ __launch_bounds__(256) void k_count(const int* __restrict__ col,
                                               int* __restrict__ cnt,
                                               int* __restrict__ bcnt) {
    __shared__ int hist[NBUK];
    const int tid = threadIdx.x;
    for (int i = tid; i < NBUK; i += 256) hist[i] = 0;
    __syncthreads();
    const int e0 = blockIdx.x * EPB;
    for (int e = e0 + tid; e < e0 + EPB && e < NE; e += 256) {
        int c = col[e];
        atomicAdd(&cnt[c], 1);
        atomicAdd(&hist[c >> 9], 1);
    }
    __syncthreads();
    for (int i = tid; i < NBUK; i += 256) {
        int h = hist[i];
        if (h) atomicAdd(&bcnt[i], h);
    }
}

// block-local exclusive scan over 1024 elems; bsums[b] = block total
__global__ void k_scan1(const int* __restrict__ cnt, int* __restrict__ row_ptr,
                        int* __restrict__ bsums) {
    __shared__ int s[256];
    const int tid = threadIdx.x;
    const int base = blockIdx.x * 1024 + tid * 4;
    int v0 = 0, v1 = 0, v2 = 0, v3 = 0;
    if (base + 0 < NN) v0 = cnt[base + 0];
    if (base + 1 < NN) v1 = cnt[base + 1];
    if (base + 2 < NN) v2 = cnt[base + 2];
    if (base + 3 < NN) v3 = cnt[base + 3];
    s[tid] = v0 + v1 + v2 + v3;
    __syncthreads();
    for (int off = 1; off < 256; off <<= 1) {
        int t = 0;
        if (tid >= off) t = s[tid - off];
        __syncthreads();
        if (tid >= off) s[tid] += t;
        __syncthreads();
    }
    int excl = (tid == 0) ? 0 : s[tid - 1];
    if (base + 0 < NN) row_ptr[base + 0] = excl;
    if (base + 1 < NN) row_ptr[base + 1] = excl + v0;
    if (base + 2 < NN) row_ptr[base + 2] = excl + v0 + v1;
    if (base + 3 < NN) row_ptr[base + 3] = excl + v0 + v1 + v2;
    if (tid == 255) bsums[blockIdx.x] = s[255];
}

// serial scans: block sums (98) + bucket counts (196)
__global__ void k_scan2(int* __restrict__ bsums, int nb, int* __restrict__ row_ptr,
                        const int* __restrict__ bcnt, int* __restrict__ bbase,
                        int* __restrict__ bcur) {
    if (threadIdx.x == 0 && blockIdx.x == 0) {
        int acc = 0;
        for (int i = 0; i < nb; ++i) { int t = bsums[i]; bsums[i] = acc; acc += t; }
        row_ptr[NN] = acc;
        int a2 = 0;
        for (int i = 0; i < NBUK; ++i) { int t = bcnt[i]; bbase[i] = a2; bcur[i] = a2; a2 += t; }
        bbase[NBUK] = a2;
    }
}

__global__ void k_finalize(const int* __restrict__ cnt, const int* __restrict__ bsums,
                           int* __restrict__ row_ptr, int* __restrict__ cursor,
                           float* __restrict__ dis) {
    int i = blockIdx.x * 256 + threadIdx.x;
    if (i < NN) {
        int rp = row_ptr[i] + bsums[i >> 10];
        row_ptr[i] = rp;
        cursor[i] = rp;
        dis[i] = rsqrtf((float)cnt[i] + 1.0f);
    }
}

// bin edges into bucket-grouped ebuf via per-block reservations
__global__ __launch_bounds__(256) void k_bin(const int* __restrict__ row,
                                             const int* __restrict__ col,
                                             int* __restrict__ bcur,
                                             int2* __restrict__ ebuf) {
    __shared__ int hist[NBUK];
    const int tid = threadIdx.x;
    for (int i = tid; i < NBUK; i += 256) hist[i] = 0;
    __syncthreads();
    const int e0 = blockIdx.x * EPB;
    for (int e = e0 + tid; e < e0 + EPB && e < NE; e += 256)
        atomicAdd(&hist[col[e] >> 9], 1);
    __syncthreads();
    // reserve contiguous ranges; hist[i] becomes the running local cursor
    for (int i = tid; i < NBUK; i += 256) {
        int c = hist[i];
        hist[i] = c ? atomicAdd(&bcur[i], c) : 0;
    }
    __syncthreads();
    for (int e = e0 + tid; e < e0 + EPB && e < NE; e += 256) {
        int c = col[e];
        int pos = atomicAdd(&hist[c >> 9], 1);
        ebuf[pos] = make_int2(row[e], c);
    }
}

// per-bucket scatter: block b owns bucket b's edge range + its 512-node cursors
__global__ __launch_bounds__(256) void k_scatter2(const int2* __restrict__ ebuf,
                                                  const int* __restrict__ bbase,
                                                  int* __restrict__ cursor,
                                                  int* __restrict__ srcs) {
    const int b = blockIdx.x;
    const int s = bbase[b], e = bbase[b + 1];
    for (int i = s + threadIdx.x; i < e; i += 256) {
        int2 rc = ebuf[i];
        int pos = atomicAdd(&cursor[rc.y], 1);
        srcs[pos] = rc.x;
    }
}

// ====== dense GEMM: out[r][f] = sum_k act(in[r][k]) * W[k][f], 4 rows/thread ======

template <bool RELU>
__global__ __launch_bounds__(256, 2) void k_gemm(const float* __restrict__ in,
                                                 const float* __restrict__ W,
                                                 float* __restrict__ out) {
    __shared__ float Ws[FD * FD];    // 64 KB
    __shared__ float xs[32][FD];     // 16 KB

    const int tid = threadIdx.x;
    {
        const float4* W4 = (const float4*)W;
        float4* Ws4 = (float4*)Ws;
#pragma unroll
        for (int i = 0; i < 16; ++i) Ws4[tid + 256 * i] = W4[tid + 256 * i];
    }

    const int f4 = tid & 31;        // output float4 column
    const int rq = tid >> 5;        // row quad 0..7 -> rows rq*4..rq*4+3

    for (int g = blockIdx.x; g < NN / 32; g += gridDim.x) {
        const int row0 = g * 32;
        __syncthreads();
        {
            const float4* in4 = (const float4*)(in + (size_t)row0 * FD);
            float4* xs4 = (float4*)xs;
#pragma unroll
            for (int i = 0; i < 4; ++i) {
                float4 v = in4[tid + 256 * i];
                if (RELU) {
                    v.x = fmaxf(v.x, 0.0f); v.y = fmaxf(v.y, 0.0f);
                    v.z = fmaxf(v.z, 0.0f); v.w = fmaxf(v.w, 0.0f);
                }
                xs4[tid + 256 * i] = v;
            }
        }
        __syncthreads();

        float4 a0 = {0,0,0,0}, a1 = {0,0,0,0}, a2 = {0,0,0,0}, a3 = {0,0,0,0};
        const float4* Ws4 = (const float4*)Ws;
#pragma unroll 8
        for (int k = 0; k < FD; ++k) {
            const float4 wv = Ws4[k * 32 + f4];
            const float x0 = xs[rq * 4 + 0][k];
            const float x1 = xs[rq * 4 + 1][k];
            const float x2 = xs[rq * 4 + 2][k];
            const float x3 = xs[rq * 4 + 3][k];
            a0.x += x0 * wv.x; a0.y += x0 * wv.y; a0.z += x0 * wv.z; a0.w += x0 * wv.w;
            a1.x += x1 * wv.x; a1.y += x1 * wv.y; a1.z += x1 * wv.z; a1.w += x1 * wv.w;
            a2.x += x2 * wv.x; a2.y += x2 * wv.y; a2.z += x2 * wv.z; a2.w += x2 * wv.w;
            a3.x += x3 * wv.x; a3.y += x3 * wv.y; a3.z += x3 * wv.z; a3.w += x3 * wv.w;
        }
        float4* o4 = (float4*)(out + (size_t)row0 * FD);
        o4[(rq * 4 + 0) * 32 + f4] = a0;
        o4[(rq * 4 + 1) * 32 + f4] = a1;
        o4[(rq * 4 + 2) * 32 + f4] = a2;
        o4[(rq * 4 + 3) * 32 + f4] = a3;
    }
}

// ================= aggregation by gather =================

__global__ __launch_bounds__(256) void k_agg_gather(const float* __restrict__ h,
                                                    const float* __restrict__ b,
                                                    const float* __restrict__ dis,
                                                    const int* __restrict__ row_ptr,
                                                    const int* __restrict__ srcs,
                                                    float* __restrict__ out) {
    const int v = (blockIdx.x * 256 + threadIdx.x) >> 5;
    if (v >= NN) return;
    const int f4 = threadIdx.x & 31;
    const float4* h4 = (const float4*)h;

    const float dv = dis[v];
    float4 acc = ((const float4*)b)[f4];
    {
        const float sl = dv * dv;
        float4 hv = h4[(size_t)v * 32 + f4];
        acc.x += sl * hv.x; acc.y += sl * hv.y;
        acc.z += sl * hv.z; acc.w += sl * hv.w;
    }

    int e = row_ptr[v];
    const int end = row_ptr[v + 1];
    for (; e + 1 < end; e += 2) {
        const int s0 = srcs[e], s1 = srcs[e + 1];
        const float w0 = dv * dis[s0];
        const float w1 = dv * dis[s1];
        const float4 a0 = h4[(size_t)s0 * 32 + f4];
        const float4 a1 = h4[(size_t)s1 * 32 + f4];
        acc.x += w0 * a0.x + w1 * a1.x;
        acc.y += w0 * a0.y + w1 * a1.y;
        acc.z += w0 * a0.z + w1 * a1.z;
        acc.w += w0 * a0.w + w1 * a1.w;
    }
    if (e < end) {
        const int s0 = srcs[e];
        const float w0 = dv * dis[s0];
        const float4 a0 = h4[(size_t)s0 * 32 + f4];
        acc.x += w0 * a0.x; acc.y += w0 * a0.y;
        acc.z += w0 * a0.z; acc.w += w0 * a0.w;
    }
    ((float4*)out)[(size_t)v * 32 + f4] = acc;
}

// ================= fallback (R1 atomic path) =================

__global__ void fb_deg_init(float* __restrict__ deg) {
    int i = blockIdx.x * 256 + threadIdx.x;
    if (i < NN) deg[i] = 1.0f;
}
__global__ void fb_deg_count(const int* __restrict__ col, float* __restrict__ deg) {
    int e = blockIdx.x * 256 + threadIdx.x;
    if (e < NE) { int c = col[e]; if ((unsigned)c < NN) unsafeAtomicAdd(&deg[c], 1.0f); }
}
__global__ void fb_dis(const float* __restrict__ deg, float* __restrict__ dis) {
    int i = blockIdx.x * 256 + threadIdx.x;
    if (i < NN) dis[i] = rsqrtf(deg[i]);
}
__global__ __launch_bounds__(256) void fb_agg_init(const float* __restrict__ h,
                                                   const float* __restrict__ b,
                                                   const float* __restrict__ dis,
                                                   float* __restrict__ out) {
    int i4 = blockIdx.x * 256 + threadIdx.x;
    if (i4 >= NN * FD / 4) return;
    int v = i4 >> 5, f4 = i4 & 31;
    float d = dis[v], sl = d * d;
    float4 hv = ((const float4*)h)[i4];
    const float4 bv = ((const float4*)b)[f4];
    float4 o = {bv.x + sl * hv.x, bv.y + sl * hv.y, bv.z + sl * hv.z, bv.w + sl * hv.w};
    ((float4*)out)[i4] = o;
}
__global__ __launch_bounds__(256) void fb_agg_edges(const int* __restrict__ row,
                                                    const int* __restrict__ col,
                                                    const float* __restrict__ dis,
                                                    const float* __restrict__ h,
                                                    float* __restrict__ out) {
    const int e = blockIdx.x * 8 + (threadIdx.x >> 5);
    const int f4 = threadIdx.x & 31;
    if (e >= NE) return;
    const int r = row[e], c = col[e];
    if ((unsigned)r >= NN || (unsigned)c >= NN) return;
    const float ne = dis[r] * dis[c];
    const float4 hv = ((const float4*)(h + (size_t)r * FD))[f4];
    float* op = out + (size_t)c * FD + f4 * 4;
    unsafeAtomicAdd(op + 0, ne * hv.x);
    unsafeAtomicAdd(op + 1, ne * hv.y);
    unsafeAtomicAdd(op + 2, ne * hv.z);
    unsafeAtomicAdd(op + 3, ne * hv.w);
}

// ================= launch =================

extern "C" void kernel_launch(void* const* d_in, const int* in_sizes, int n_in,
                              void* d_out, int out_size, void* d_ws, size_t ws_size,
                              hipStream_t stream) {
    const float* x  = (const float*)d_in[0];
    const int*   ei = (const int*)d_in[1];
    const float* W1 = (const float*)d_in[2];
    const float* b1 = (const float*)d_in[3];
    const float* W2 = (const float*)d_in[4];
    const float* b2 = (const float*)d_in[5];
    float* out = (float*)d_out;

    const int* row = ei;        // source (gather side)
    const int* col = ei + NE;   // target (scatter side)

    // ---- workspace layout ----
    int*   cnt     = (int*)d_ws;            // NN
    int*   bcnt    = cnt + NN;              // 256
    int*   row_ptr = bcnt + 256;            // NN+32
    int*   cursor  = row_ptr + NN + 32;     // NN
    int*   bsums   = cursor + NN;           // 128
    int*   bbase   = bsums + 128;           // 200 (NBUK+1 used)
    int*   bcur    = bbase + 200;           // 200
    float* dis     = (float*)(bcur + 200);  // NN
    float* h       = dis + NN;              // NN*FD
    float* agg     = h + (size_t)NN * FD;   // NN*FD
    int*   srcs    = (int*)(agg + (size_t)NN * FD);  // NE
    int2*  ebuf    = (int2*)agg;            // alias: dead before gather writes agg
    const size_t NEED = ((size_t)(5 * NN + 984)) * 4 + 2 * (size_t)NN * FD * 4
                        + (size_t)NE * 4;

    if (ws_size >= NEED) {
        // ---- CSC build ----
        k_zero<<<(NN + 256 + 255) / 256, 256, 0, stream>>>(cnt, NN + 256);
        k_count<<<NB_E, 256, 0, stream>>>(col, cnt, bcnt);
        k_scan1<<<SCAN_BLOCKS, 256, 0, stream>>>(cnt, row_ptr, bsums);
        k_scan2<<<1, 64, 0, stream>>>(bsums, SCAN_BLOCKS, row_ptr, bcnt, bbase, bcur);
        k_finalize<<<(NN + 255) / 256, 256, 0, stream>>>(cnt, bsums, row_ptr, cursor, dis);
        k_bin<<<NB_E, 256, 0, stream>>>(row, col, bcur, ebuf);
        k_scatter2<<<NBUK, 256, 0, stream>>>(ebuf, bbase, cursor, srcs);

        // ---- layer 1 ----
        k_gemm<false><<<1024, 256, 0, stream>>>(x, W1, h);
        k_agg_gather<<<NN * 32 / 256, 256, 0, stream>>>(h, b1, dis, row_ptr, srcs, agg);
        // ---- layer 2 ----
        k_gemm<true><<<1024, 256, 0, stream>>>(agg, W2, h);
        k_agg_gather<<<NN * 32 / 256, 256, 0, stream>>>(h, b2, dis, row_ptr, srcs, out);
    } else {
        // fallback: R1 atomic path
        float* fdeg = (float*)d_ws;
        float* fdis = fdeg + NN;
        float* fh   = fdis + NN;
        float* fagg = fh + (size_t)NN * FD;
        fb_deg_init<<<(NN + 255) / 256, 256, 0, stream>>>(fdeg);
        fb_deg_count<<<(NE + 255) / 256, 256, 0, stream>>>(col, fdeg);
        fb_dis<<<(NN + 255) / 256, 256, 0, stream>>>(fdeg, fdis);
        k_gemm<false><<<1024, 256, 0, stream>>>(x, W1, fh);
        fb_agg_init<<<NN * FD / 4 / 256, 256, 0, stream>>>(fh, b1, fdis, fagg);
        fb_agg_edges<<<NE / 8, 256, 0, stream>>>(row, col, fdis, fh, fagg);
        k_gemm<true><<<1024, 256, 0, stream>>>(fagg, W2, fh);
        fb_agg_init<<<NN * FD / 4 / 256, 256, 0, stream>>>(fh, b2, fdis, out);
        fb_agg_edges<<<NE / 8, 256, 0, stream>>>(row, col, fdis, fh, out);
    }
}

// Round 5
// 471.177 us; speedup vs baseline: 11.9947x; 1.1762x over previous
//
#include <hip/hip_runtime.h>

#define NN 100000
#define NE 1600000
#define FD 128
#define SCAN_BLOCKS 98      // ceil(NN / 1024)
#define NBUK 196            // ceil(NN / 512), bucket = col >> 9
#define EPB 4096            // edges per block in edge-pass kernels
#define NB_E 391            // ceil(NE / EPB)

typedef unsigned int  u32;
typedef unsigned short u16;

__device__ __forceinline__ u16 f2bf(float f) {
    u32 u = __float_as_uint(f);
    u32 r = (u + 0x7FFFu + ((u >> 16) & 1u)) >> 16;   // RNE
    return (u16)r;
}

// acc += wt * bf16x4(u)
__device__ __forceinline__ void acc4(float4& acc, float wt, uint2 u) {
    acc.x += wt * __uint_as_float(u.x << 16);
    acc.y += wt * __uint_as_float(u.x & 0xffff0000u);
    acc.z += wt * __uint_as_float(u.y << 16);
    acc.w += wt * __uint_as_float(u.y & 0xffff0000u);
}

// ================= graph build (CSC by destination, bucketed) =================

__global__ void k_zero(int* __restrict__ p, int n) {
    int i = blockIdx.x * 256 + threadIdx.x;
    if (i < n) p[i] = 0;
}

// fused: per-node degree count + per-bucket histogram
__global__ __launch_bounds__(256) void k_count(const int* __restrict__ col,
                                               int* __restrict__ cnt,
                                               int* __restrict__ bcnt) {
    __shared__ int hist[NBUK];
    const int tid = threadIdx.x;
    for (int i = tid; i < NBUK; i += 256) hist[i] = 0;
    __syncthreads();
    const int e0 = blockIdx.x * EPB;
    for (int e = e0 + tid; e < e0 + EPB && e < NE; e += 256) {
        int c = col[e];
        atomicAdd(&cnt[c], 1);
        atomicAdd(&hist[c >> 9], 1);
    }
    __syncthreads();
    for (int i = tid; i < NBUK; i += 256) {
        int h = hist[i];
        if (h) atomicAdd(&bcnt[i], h);
    }
}

__global__ void k_scan1(const int* __restrict__ cnt, int* __restrict__ row_ptr,
                        int* __restrict__ bsums) {
    __shared__ int s[256];
    const int tid = threadIdx.x;
    const int base = blockIdx.x * 1024 + tid * 4;
    int v0 = 0, v1 = 0, v2 = 0, v3 = 0;
    if (base + 0 < NN) v0 = cnt[base + 0];
    if (base + 1 < NN) v1 = cnt[base + 1];
    if (base + 2 < NN) v2 = cnt[base + 2];
    if (base + 3 < NN) v3 = cnt[base + 3];
    s[tid] = v0 + v1 + v2 + v3;
    __syncthreads();
    for (int off = 1; off < 256; off <<= 1) {
        int t = 0;
        if (tid >= off) t = s[tid - off];
        __syncthreads();
        if (tid >= off) s[tid] += t;
        __syncthreads();
    }
    int excl = (tid == 0) ? 0 : s[tid - 1];
    if (base + 0 < NN) row_ptr[base + 0] = excl;
    if (base + 1 < NN) row_ptr[base + 1] = excl + v0;
    if (base + 2 < NN) row_ptr[base + 2] = excl + v0 + v1;
    if (base + 3 < NN) row_ptr[base + 3] = excl + v0 + v1 + v2;
    if (tid == 255) bsums[blockIdx.x] = s[255];
}

__global__ void k_scan2(int* __restrict__ bsums, int nb, int* __restrict__ row_ptr,
                        const int* __restrict__ bcnt, int* __restrict__ bbase,
                        int* __restrict__ bcur) {
    if (threadIdx.x == 0 && blockIdx.x == 0) {
        int acc = 0;
        for (int i = 0; i < nb; ++i) { int t = bsums[i]; bsums[i] = acc; acc += t; }
        row_ptr[NN] = acc;
        int a2 = 0;
        for (int i = 0; i < NBUK; ++i) { int t = bcnt[i]; bbase[i] = a2; bcur[i] = a2; a2 += t; }
        bbase[NBUK] = a2;
    }
}

__global__ void k_finalize(const int* __restrict__ cnt, const int* __restrict__ bsums,
                           int* __restrict__ row_ptr, int* __restrict__ cursor,
                           float* __restrict__ dis) {
    int i = blockIdx.x * 256 + threadIdx.x;
    if (i < NN) {
        int rp = row_ptr[i] + bsums[i >> 10];
        row_ptr[i] = rp;
        cursor[i] = rp;
        dis[i] = rsqrtf((float)cnt[i] + 1.0f);
    }
}

__global__ __launch_bounds__(256) void k_bin(const int* __restrict__ row,
                                             const int* __restrict__ col,
                                             int* __restrict__ bcur,
                                             int2* __restrict__ ebuf) {
    __shared__ int hist[NBUK];
    const int tid = threadIdx.x;
    for (int i = tid; i < NBUK; i += 256) hist[i] = 0;
    __syncthreads();
    const int e0 = blockIdx.x * EPB;
    for (int e = e0 + tid; e < e0 + EPB && e < NE; e += 256)
        atomicAdd(&hist[col[e] >> 9], 1);
    __syncthreads();
    for (int i = tid; i < NBUK; i += 256) {
        int c = hist[i];
        hist[i] = c ? atomicAdd(&bcur[i], c) : 0;
    }
    __syncthreads();
    for (int e = e0 + tid; e < e0 + EPB && e < NE; e += 256) {
        int c = col[e];
        int pos = atomicAdd(&hist[c >> 9], 1);
        ebuf[pos] = make_int2(row[e], c);
    }
}

__global__ __launch_bounds__(256) void k_scatter2(const int2* __restrict__ ebuf,
                                                  const int* __restrict__ bbase,
                                                  int* __restrict__ cursor,
                                                  int* __restrict__ srcs) {
    const int b = blockIdx.x;
    const int s = bbase[b], e = bbase[b + 1];
    for (int i = s + threadIdx.x; i < e; i += 256) {
        int2 rc = ebuf[i];
        int pos = atomicAdd(&cursor[rc.y], 1);
        srcs[pos] = rc.x;
    }
}

// ====== dense GEMM: hb[r][f] = bf16( sum_k act(in[r][k]) * W[k][f] ) ======

template <bool RELU>
__global__ __launch_bounds__(256, 2) void k_gemm(const float* __restrict__ in,
                                                 const float* __restrict__ W,
                                                 u16* __restrict__ out) {
    __shared__ float Ws[FD * FD];    // 64 KB
    __shared__ float xs[32][FD];     // 16 KB

    const int tid = threadIdx.x;
    {
        const float4* W4 = (const float4*)W;
        float4* Ws4 = (float4*)Ws;
#pragma unroll
        for (int i = 0; i < 16; ++i) Ws4[tid + 256 * i] = W4[tid + 256 * i];
    }

    const int f4 = tid & 31;
    const int rq = tid >> 5;

    for (int g = blockIdx.x; g < NN / 32; g += gridDim.x) {
        const int row0 = g * 32;
        __syncthreads();
        {
            const float4* in4 = (const float4*)(in + (size_t)row0 * FD);
            float4* xs4 = (float4*)xs;
#pragma unroll
            for (int i = 0; i < 4; ++i) {
                float4 v = in4[tid + 256 * i];
                if (RELU) {
                    v.x = fmaxf(v.x, 0.0f); v.y = fmaxf(v.y, 0.0f);
                    v.z = fmaxf(v.z, 0.0f); v.w = fmaxf(v.w, 0.0f);
                }
                xs4[tid + 256 * i] = v;
            }
        }
        __syncthreads();

        float4 a0 = {0,0,0,0}, a1 = {0,0,0,0}, a2 = {0,0,0,0}, a3 = {0,0,0,0};
        const float4* Ws4 = (const float4*)Ws;
#pragma unroll 8
        for (int k = 0; k < FD; ++k) {
            const float4 wv = Ws4[k * 32 + f4];
            const float x0 = xs[rq * 4 + 0][k];
            const float x1 = xs[rq * 4 + 1][k];
            const float x2 = xs[rq * 4 + 2][k];
            const float x3 = xs[rq * 4 + 3][k];
            a0.x += x0 * wv.x; a0.y += x0 * wv.y; a0.z += x0 * wv.z; a0.w += x0 * wv.w;
            a1.x += x1 * wv.x; a1.y += x1 * wv.y; a1.z += x1 * wv.z; a1.w += x1 * wv.w;
            a2.x += x2 * wv.x; a2.y += x2 * wv.y; a2.z += x2 * wv.z; a2.w += x2 * wv.w;
            a3.x += x3 * wv.x; a3.y += x3 * wv.y; a3.z += x3 * wv.z; a3.w += x3 * wv.w;
        }
        ushort4* o4 = (ushort4*)out;
        const size_t rb = (size_t)row0 * 32;
        ushort4 s0 = {f2bf(a0.x), f2bf(a0.y), f2bf(a0.z), f2bf(a0.w)};
        ushort4 s1 = {f2bf(a1.x), f2bf(a1.y), f2bf(a1.z), f2bf(a1.w)};
        ushort4 s2 = {f2bf(a2.x), f2bf(a2.y), f2bf(a2.z), f2bf(a2.w)};
        ushort4 s3 = {f2bf(a3.x), f2bf(a3.y), f2bf(a3.z), f2bf(a3.w)};
        o4[rb + (rq * 4 + 0) * 32 + f4] = s0;
        o4[rb + (rq * 4 + 1) * 32 + f4] = s1;
        o4[rb + (rq * 4 + 2) * 32 + f4] = s2;
        o4[rb + (rq * 4 + 3) * 32 + f4] = s3;
    }
}

// ================= aggregation by gather (bf16 payload) =================
// out[v] = b + dis[v]^2 * h[v] + sum_e dis[v]*dis[src] * h[src]
__global__ __launch_bounds__(256) void k_agg_gather(const u16* __restrict__ hb,
                                                    const float* __restrict__ b,
                                                    const float* __restrict__ dis,
                                                    const int* __restrict__ row_ptr,
                                                    const int* __restrict__ srcs,
                                                    float* __restrict__ out) {
    const int v = (blockIdx.x * 256 + threadIdx.x) >> 5;
    if (v >= NN) return;
    const int f4 = threadIdx.x & 31;          // 4 features per thread
    const uint2* h2 = (const uint2*)hb;       // 4 bf16 per uint2

    const float dv = dis[v];
    float4 acc = ((const float4*)b)[f4];
    {
        const float sl = dv * dv;
        uint2 u = h2[(size_t)v * 32 + f4];
        acc4(acc, sl, u);
    }

    int e = row_ptr[v];
    const int end = row_ptr[v + 1];
    for (; e + 3 < end; e += 4) {
        const int s0 = srcs[e], s1 = srcs[e + 1], s2 = srcs[e + 2], s3 = srcs[e + 3];
        const float w0 = dv * dis[s0];
        const float w1 = dv * dis[s1];
        const float w2 = dv * dis[s2];
        const float w3 = dv * dis[s3];
        const uint2 u0 = h2[(size_t)s0 * 32 + f4];
        const uint2 u1 = h2[(size_t)s1 * 32 + f4];
        const uint2 u2 = h2[(size_t)s2 * 32 + f4];
        const uint2 u3 = h2[(size_t)s3 * 32 + f4];
        acc4(acc, w0, u0); acc4(acc, w1, u1); acc4(acc, w2, u2); acc4(acc, w3, u3);
    }
    for (; e < end; ++e) {
        const int s0 = srcs[e];
        const float w0 = dv * dis[s0];
        const uint2 u0 = h2[(size_t)s0 * 32 + f4];
        acc4(acc, w0, u0);
    }
    ((float4*)out)[(size_t)v * 32 + f4] = acc;
}

// ================= launch =================

extern "C" void kernel_launch(void* const* d_in, const int* in_sizes, int n_in,
                              void* d_out, int out_size, void* d_ws, size_t ws_size,
                              hipStream_t stream) {
    const float* x  = (const float*)d_in[0];
    const int*   ei = (const int*)d_in[1];
    const float* W1 = (const float*)d_in[2];
    const float* b1 = (const float*)d_in[3];
    const float* W2 = (const float*)d_in[4];
    const float* b2 = (const float*)d_in[5];
    float* out = (float*)d_out;

    const int* row = ei;        // source (gather side)
    const int* col = ei + NE;   // target (scatter side)

    // ---- workspace layout ----
    int*   cnt     = (int*)d_ws;            // NN
    int*   bcnt    = cnt + NN;              // 256
    int*   row_ptr = bcnt + 256;            // NN+32
    int*   cursor  = row_ptr + NN + 32;     // NN
    int*   bsums   = cursor + NN;           // 128
    int*   bbase   = bsums + 128;           // 200
    int*   bcur    = bbase + 200;           // 200
    float* dis     = (float*)(bcur + 200);  // NN
    u16*   hb      = (u16*)(dis + NN);      // NN*FD bf16 (25.6 MB)
    float* agg     = (float*)(hb + (size_t)NN * FD);   // NN*FD f32
    int*   srcs    = (int*)(agg + (size_t)NN * FD);    // NE
    int2*  ebuf    = (int2*)agg;            // alias: dead before gather writes agg

    // ---- CSC build ----
    k_zero<<<(NN + 256 + 255) / 256, 256, 0, stream>>>(cnt, NN + 256);
    k_count<<<NB_E, 256, 0, stream>>>(col, cnt, bcnt);
    k_scan1<<<SCAN_BLOCKS, 256, 0, stream>>>(cnt, row_ptr, bsums);
    k_scan2<<<1, 64, 0, stream>>>(bsums, SCAN_BLOCKS, row_ptr, bcnt, bbase, bcur);
    k_finalize<<<(NN + 255) / 256, 256, 0, stream>>>(cnt, bsums, row_ptr, cursor, dis);
    k_bin<<<NB_E, 256, 0, stream>>>(row, col, bcur, ebuf);
    k_scatter2<<<NBUK, 256, 0, stream>>>(ebuf, bbase, cursor, srcs);

    // ---- layer 1 ----
    k_gemm<false><<<1024, 256, 0, stream>>>(x, W1, hb);
    k_agg_gather<<<NN * 32 / 256, 256, 0, stream>>>(hb, b1, dis, row_ptr, srcs, agg);
    // ---- layer 2 ----
    k_gemm<true><<<1024, 256, 0, stream>>>(agg, W2, hb);
    k_agg_gather<<<NN * 32 / 256, 256, 0, stream>>>(hb, b2, dis, row_ptr, srcs, out);
}

// Round 7
// 326.784 us; speedup vs baseline: 17.2947x; 1.4419x over previous
//
#include <hip/hip_runtime.h>

#define NN 100000
#define NE 1600000
#define FD 128
#define SCAN_BLOCKS 98      // ceil(NN / 1024)
#define NBUK 196            // ceil(NN / 512), bucket = col >> 9
#define EPB 4096            // edges per block in edge-pass kernels
#define NB_E 391            // ceil(NE / EPB)
#define NGROUP 6250         // NN/16 row-groups for MFMA gemm

typedef unsigned int  u32;
typedef unsigned short u16;
typedef __bf16 bf16x8 __attribute__((ext_vector_type(8)));
typedef float  f32x4v __attribute__((ext_vector_type(4)));

__device__ __forceinline__ u16 f2bf(float f) {
    u32 u = __float_as_uint(f);
    u32 r = (u + 0x7FFFu + ((u >> 16) & 1u)) >> 16;   // RNE
    return (u16)r;
}

__device__ __forceinline__ void acc2(float& x, float& y, float wt, u32 w) {
    x += wt * __uint_as_float(w << 16);
    y += wt * __uint_as_float(w & 0xffff0000u);
}
__device__ __forceinline__ void acc8(float4& L, float4& H, float wt, uint4 u) {
    acc2(L.x, L.y, wt, u.x); acc2(L.z, L.w, wt, u.y);
    acc2(H.x, H.y, wt, u.z); acc2(H.z, H.w, wt, u.w);
}

// ================= graph build (CSC by destination, bucketed) =================

__global__ void k_zero(int* __restrict__ p, int n) {
    int i = blockIdx.x * 256 + threadIdx.x;
    if (i < n) p[i] = 0;
}

__global__ __launch_bounds__(256) void k_count(const int* __restrict__ col,
                                               int* __restrict__ cnt,
                                               int* __restrict__ bcnt) {
    __shared__ int hist[NBUK];
    const int tid = threadIdx.x;
    for (int i = tid; i < NBUK; i += 256) hist[i] = 0;
    __syncthreads();
    const int e0 = blockIdx.x * EPB;
    for (int e = e0 + tid; e < e0 + EPB && e < NE; e += 256) {
        int c = col[e];
        atomicAdd(&cnt[c], 1);
        atomicAdd(&hist[c >> 9], 1);
    }
    __syncthreads();
    for (int i = tid; i < NBUK; i += 256) {
        int h = hist[i];
        if (h) atomicAdd(&bcnt[i], h);
    }
}

__global__ void k_scan1(const int* __restrict__ cnt, int* __restrict__ row_ptr,
                        int* __restrict__ bsums) {
    __shared__ int s[256];
    const int tid = threadIdx.x;
    const int base = blockIdx.x * 1024 + tid * 4;
    int v0 = 0, v1 = 0, v2 = 0, v3 = 0;
    if (base + 0 < NN) v0 = cnt[base + 0];
    if (base + 1 < NN) v1 = cnt[base + 1];
    if (base + 2 < NN) v2 = cnt[base + 2];
    if (base + 3 < NN) v3 = cnt[base + 3];
    s[tid] = v0 + v1 + v2 + v3;
    __syncthreads();
    for (int off = 1; off < 256; off <<= 1) {
        int t = 0;
        if (tid >= off) t = s[tid - off];
        __syncthreads();
        if (tid >= off) s[tid] += t;
        __syncthreads();
    }
    int excl = (tid == 0) ? 0 : s[tid - 1];
    if (base + 0 < NN) row_ptr[base + 0] = excl;
    if (base + 1 < NN) row_ptr[base + 1] = excl + v0;
    if (base + 2 < NN) row_ptr[base + 2] = excl + v0 + v1;
    if (base + 3 < NN) row_ptr[base + 3] = excl + v0 + v1 + v2;
    if (tid == 255) bsums[blockIdx.x] = s[255];
}

__global__ void k_scan2(int* __restrict__ bsums, int nb, int* __restrict__ row_ptr,
                        const int* __restrict__ bcnt, int* __restrict__ bbase,
                        int* __restrict__ bcur) {
    if (threadIdx.x == 0 && blockIdx.x == 0) {
        int acc = 0;
        for (int i = 0; i < nb; ++i) { int t = bsums[i]; bsums[i] = acc; acc += t; }
        row_ptr[NN] = acc;
        int a2 = 0;
        for (int i = 0; i < NBUK; ++i) { int t = bcnt[i]; bbase[i] = a2; bcur[i] = a2; a2 += t; }
        bbase[NBUK] = a2;
    }
}

__global__ void k_finalize(const int* __restrict__ cnt, const int* __restrict__ bsums,
                           int* __restrict__ row_ptr, int* __restrict__ cursor,
                           float* __restrict__ dis) {
    int i = blockIdx.x * 256 + threadIdx.x;
    if (i < NN) {
        int rp = row_ptr[i] + bsums[i >> 10];
        row_ptr[i] = rp;
        cursor[i] = rp;
        dis[i] = rsqrtf((float)cnt[i] + 1.0f);
    }
}

__global__ __launch_bounds__(256) void k_bin(const int* __restrict__ row,
                                             const int* __restrict__ col,
                                             int* __restrict__ bcur,
                                             int2* __restrict__ ebuf) {
    __shared__ int hist[NBUK];
    const int tid = threadIdx.x;
    for (int i = tid; i < NBUK; i += 256) hist[i] = 0;
    __syncthreads();
    const int e0 = blockIdx.x * EPB;
    for (int e = e0 + tid; e < e0 + EPB && e < NE; e += 256)
        atomicAdd(&hist[col[e] >> 9], 1);
    __syncthreads();
    for (int i = tid; i < NBUK; i += 256) {
        int c = hist[i];
        hist[i] = c ? atomicAdd(&bcur[i], c) : 0;
    }
    __syncthreads();
    for (int e = e0 + tid; e < e0 + EPB && e < NE; e += 256) {
        int c = col[e];
        int pos = atomicAdd(&hist[c >> 9], 1);
        ebuf[pos] = make_int2(row[e], c);
    }
}

__global__ __launch_bounds__(256) void k_scatter2(const int2* __restrict__ ebuf,
                                                  const int* __restrict__ bbase,
                                                  int* __restrict__ cursor,
                                                  int* __restrict__ srcs) {
    const int b = blockIdx.x;
    const int s = bbase[b], e = bbase[b + 1];
    for (int i = s + threadIdx.x; i < e; i += 256) {
        int2 rc = ebuf[i];
        int pos = atomicAdd(&cursor[rc.y], 1);
        srcs[pos] = rc.x;
    }
}

// ================= W pre-pack into MFMA B-fragment order (bf16) =================
// For tile t (n-block of 16), k-iter q (k-block of 32), lane l, elem j:
//   B elem = W[q*32 + (l>>4)*8 + j][t*16 + (l&15)]  stored at Wf[((t*4+q)*64+l)*8+j]
__global__ void k_packW2(const float* __restrict__ W1, const float* __restrict__ W2,
                         u16* __restrict__ Wf1, u16* __restrict__ Wf2) {
    int tid = blockIdx.x * 256 + threadIdx.x;
    if (tid >= 2048) return;
    int l = tid & 63;
    int tq = tid >> 6;
    int q = tq & 3, t = tq >> 2;
    int n = t * 16 + (l & 15);
    int k0 = q * 32 + (l >> 4) * 8;
    u32 p[4], r[4];
    for (int jj = 0; jj < 4; ++jj) {
        u16 lo1 = f2bf(W1[(size_t)(k0 + 2 * jj) * FD + n]);
        u16 hi1 = f2bf(W1[(size_t)(k0 + 2 * jj + 1) * FD + n]);
        p[jj] = (u32)lo1 | ((u32)hi1 << 16);
        u16 lo2 = f2bf(W2[(size_t)(k0 + 2 * jj) * FD + n]);
        u16 hi2 = f2bf(W2[(size_t)(k0 + 2 * jj + 1) * FD + n]);
        r[jj] = (u32)lo2 | ((u32)hi2 << 16);
    }
    *(uint4*)&Wf1[(size_t)tid * 8] = make_uint4(p[0], p[1], p[2], p[3]);
    *(uint4*)&Wf2[(size_t)tid * 8] = make_uint4(r[0], r[1], r[2], r[3]);
}

// ================= x f32 -> bf16 =================
__global__ void k_cvt(const float* __restrict__ x, u16* __restrict__ xb) {
    int i = blockIdx.x * 256 + threadIdx.x;     // 8 elems per thread
    const float4* s = (const float4*)x;
    float4 v0 = s[(size_t)i * 2];
    float4 v1 = s[(size_t)i * 2 + 1];
    uint4 p;
    p.x = (u32)f2bf(v0.x) | ((u32)f2bf(v0.y) << 16);
    p.y = (u32)f2bf(v0.z) | ((u32)f2bf(v0.w) << 16);
    p.z = (u32)f2bf(v1.x) | ((u32)f2bf(v1.y) << 16);
    p.w = (u32)f2bf(v1.z) | ((u32)f2bf(v1.w) << 16);
    ((uint4*)xb)[i] = p;
}

// ================= MFMA GEMM: out[r][f] = bf16( sum_k in[r][k] * W[k][f] ) =====
// in bf16 [M x 128], Wf pre-packed fragments, out bf16 [M x 128].
// 4 waves/block, each wave owns 16 rows; 8 n-tiles x 4 k-iters of 16x16x32.
__global__ __launch_bounds__(256, 4) void k_gemm_mfma(const u16* __restrict__ in,
                                                      const u16* __restrict__ Wf,
                                                      u16* __restrict__ out) {
    __shared__ u16 Wl[16384];   // 32 KB packed fragments = 2048 uint4
    const int tid = threadIdx.x;
    {
        const uint4* s = (const uint4*)Wf;
        uint4* d = (uint4*)Wl;
#pragma unroll
        for (int i = 0; i < 8; ++i) d[tid + 256 * i] = s[tid + 256 * i];   // 8*256 = 2048
    }
    __syncthreads();

    const int wave = tid >> 6, lane = tid & 63;
    const int gid = blockIdx.x * 4 + wave;
    if (gid >= NGROUP) return;
    const int row0 = gid * 16;
    const int lr = lane & 15;       // A row / D col
    const int lh = lane >> 4;       // k-subblock

    f32x4v acc[8];
#pragma unroll
    for (int t = 0; t < 8; ++t) { f32x4v z = {0.f, 0.f, 0.f, 0.f}; acc[t] = z; }

    const u16* arow = in + (size_t)(row0 + lr) * FD + lh * 8;
#pragma unroll
    for (int q = 0; q < 4; ++q) {
        bf16x8 a = *(const bf16x8*)(arow + q * 32);
#pragma unroll
        for (int t = 0; t < 8; ++t) {
            bf16x8 b = *(const bf16x8*)(&Wl[(size_t)(t * 4 + q) * 512 + lane * 8]);
            acc[t] = __builtin_amdgcn_mfma_f32_16x16x32_bf16(a, b, acc[t], 0, 0, 0);
        }
    }
    // D: col = t*16 + (lane&15), row = row0 + (lane>>4)*4 + j
#pragma unroll
    for (int t = 0; t < 8; ++t) {
#pragma unroll
        for (int j = 0; j < 4; ++j) {
            const int r = row0 + lh * 4 + j;
            out[(size_t)r * FD + t * 16 + lr] = f2bf(acc[t][j]);
        }
    }
}

// ================= aggregation by gather (bf16 payload, 16 lanes/node) =========
// out[v] = b + dis[v]^2 * h[v] + sum_e dis[v]*dis[src] * h[src]
// BF16OUT: write relu(out) as bf16 (feeds next GEMM); else f32.
template <bool BF16OUT>
__global__ __launch_bounds__(256) void k_agg_gather(const u16* __restrict__ hb,
                                                    const float* __restrict__ b,
                                                    const float* __restrict__ dis,
                                                    const int* __restrict__ row_ptr,
                                                    const int* __restrict__ srcs,
                                                    void* __restrict__ outv) {
    const int v = (blockIdx.x * 256 + threadIdx.x) >> 4;
    if (v >= NN) return;
    const int f8 = threadIdx.x & 15;          // 8 features per thread
    const uint4* h4 = (const uint4*)hb;       // 16 uint4 per node row

    const float dv = dis[v];
    float4 aL = ((const float4*)b)[f8 * 2];
    float4 aH = ((const float4*)b)[f8 * 2 + 1];
    {
        const float sl = dv * dv;
        uint4 u = h4[(size_t)v * 16 + f8];
        acc8(aL, aH, sl, u);
    }

    int e = row_ptr[v];
    const int end = row_ptr[v + 1];
    for (; e + 3 < end; e += 4) {
        const int s0 = srcs[e], s1 = srcs[e + 1], s2 = srcs[e + 2], s3 = srcs[e + 3];
        const float w0 = dv * dis[s0];
        const float w1 = dv * dis[s1];
        const float w2 = dv * dis[s2];
        const float w3 = dv * dis[s3];
        const uint4 u0 = h4[(size_t)s0 * 16 + f8];
        const uint4 u1 = h4[(size_t)s1 * 16 + f8];
        const uint4 u2 = h4[(size_t)s2 * 16 + f8];
        const uint4 u3 = h4[(size_t)s3 * 16 + f8];
        acc8(aL, aH, w0, u0); acc8(aL, aH, w1, u1);
        acc8(aL, aH, w2, u2); acc8(aL, aH, w3, u3);
    }
    for (; e < end; ++e) {
        const int s0 = srcs[e];
        const float w0 = dv * dis[s0];
        const uint4 u0 = h4[(size_t)s0 * 16 + f8];
        acc8(aL, aH, w0, u0);
    }

    if (BF16OUT) {
        uint4 p;
        p.x = (u32)f2bf(fmaxf(aL.x, 0.f)) | ((u32)f2bf(fmaxf(aL.y, 0.f)) << 16);
        p.y = (u32)f2bf(fmaxf(aL.z, 0.f)) | ((u32)f2bf(fmaxf(aL.w, 0.f)) << 16);
        p.z = (u32)f2bf(fmaxf(aH.x, 0.f)) | ((u32)f2bf(fmaxf(aH.y, 0.f)) << 16);
        p.w = (u32)f2bf(fmaxf(aH.z, 0.f)) | ((u32)f2bf(fmaxf(aH.w, 0.f)) << 16);
        ((uint4*)outv)[(size_t)v * 16 + f8] = p;
    } else {
        float4* o = (float4*)outv;
        o[(size_t)v * 32 + f8 * 2] = aL;
        o[(size_t)v * 32 + f8 * 2 + 1] = aH;
    }
}

// ================= launch =================

extern "C" void kernel_launch(void* const* d_in, const int* in_sizes, int n_in,
                              void* d_out, int out_size, void* d_ws, size_t ws_size,
                              hipStream_t stream) {
    const float* x  = (const float*)d_in[0];
    const int*   ei = (const int*)d_in[1];
    const float* W1 = (const float*)d_in[2];
    const float* b1 = (const float*)d_in[3];
    const float* W2 = (const float*)d_in[4];
    const float* b2 = (const float*)d_in[5];
    float* out = (float*)d_out;

    const int* row = ei;        // source (gather side)
    const int* col = ei + NE;   // target (scatter side)

    // ---- workspace layout (256B-aligned regions) ----
    char* base = (char*)d_ws;
    size_t o = 0;
    auto take = [&](size_t bytes) -> void* {
        void* p = base + o;
        o += (bytes + 255) & ~(size_t)255;
        return p;
    };
    int*   cnt     = (int*)take((size_t)NN * 4);
    int*   row_ptr = (int*)take((size_t)(NN + 32) * 4);
    int*   cursor  = (int*)take((size_t)NN * 4);
    int*   bsums   = (int*)take(128 * 4);
    int*   bbase   = (int*)take(256 * 4);
    int*   bcur    = (int*)take(256 * 4);
    int*   bcnt    = (int*)take(256 * 4);
    float* dis     = (float*)take((size_t)NN * 4);
    u16*   Wf1     = (u16*)take(16384 * 2);
    u16*   Wf2     = (u16*)take(16384 * 2);
    u16*   hb      = (u16*)take((size_t)NN * FD * 2);
    u16*   aggb    = (u16*)take((size_t)NN * FD * 2);
    int*   srcs    = (int*)take((size_t)NE * 4);
    void*  alias   = take((size_t)NN * FD * 2);   // ebuf (12.8MB) then xb (25.6MB)
    int2*  ebuf    = (int2*)alias;
    u16*   xb      = (u16*)alias;

    // ---- CSC build ----
    k_zero<<<(NN + 255) / 256, 256, 0, stream>>>(cnt, NN);
    k_zero<<<1, 256, 0, stream>>>(bcnt, 256);
    k_count<<<NB_E, 256, 0, stream>>>(col, cnt, bcnt);
    k_scan1<<<SCAN_BLOCKS, 256, 0, stream>>>(cnt, row_ptr, bsums);
    k_scan2<<<1, 64, 0, stream>>>(bsums, SCAN_BLOCKS, row_ptr, bcnt, bbase, bcur);
    k_finalize<<<(NN + 255) / 256, 256, 0, stream>>>(cnt, bsums, row_ptr, cursor, dis);
    k_bin<<<NB_E, 256, 0, stream>>>(row, col, bcur, ebuf);
    k_scatter2<<<NBUK, 256, 0, stream>>>(ebuf, bbase, cursor, srcs);

    // ---- weights pack + x conversion (x overwrites dead ebuf) ----
    k_packW2<<<8, 256, 0, stream>>>(W1, W2, Wf1, Wf2);
    k_cvt<<<NGROUP, 256, 0, stream>>>(x, xb);

    // ---- layer 1 ----
    k_gemm_mfma<<<(NGROUP + 3) / 4, 256, 0, stream>>>(xb, Wf1, hb);
    k_agg_gather<true><<<NN * 16 / 256, 256, 0, stream>>>(hb, b1, dis, row_ptr, srcs, aggb);
    // ---- layer 2 ----
    k_gemm_mfma<<<(NGROUP + 3) / 4, 256, 0, stream>>>(aggb, Wf2, hb);
    k_agg_gather<false><<<NN * 16 / 256, 256, 0, stream>>>(hb, b2, dis, row_ptr, srcs, out);
}

// Round 8
// 245.419 us; speedup vs baseline: 23.0284x; 1.3315x over previous
//
#include <hip/hip_runtime.h>

#define NN 100000
#define NE 1600000
#define FD 128
#define NBUK 196            // ceil(NN / 512), bucket = col >> 9
#define EPB 2048            // edges per block in edge-pass kernels
#define NB_E 782            // ceil(NE / EPB)
#define NGROUP 6250         // NN/16 row-groups for MFMA gemm

typedef unsigned int  u32;
typedef unsigned short u16;
typedef __bf16 bf16x8 __attribute__((ext_vector_type(8)));
typedef float  f32x4v __attribute__((ext_vector_type(4)));

__device__ __forceinline__ u16 f2bf(float f) {
    u32 u = __float_as_uint(f);
    u32 r = (u + 0x7FFFu + ((u >> 16) & 1u)) >> 16;   // RNE
    return (u16)r;
}

__device__ __forceinline__ void acc2(float& x, float& y, float wt, u32 w) {
    x += wt * __uint_as_float(w << 16);
    y += wt * __uint_as_float(w & 0xffff0000u);
}
__device__ __forceinline__ void acc8(float4& L, float4& H, float wt, uint4 u) {
    acc2(L.x, L.y, wt, u.x); acc2(L.z, L.w, wt, u.y);
    acc2(H.x, H.y, wt, u.z); acc2(H.z, H.w, wt, u.w);
}

// ================= graph build (bucketed CSC, LDS-only per-node atomics) =======

__global__ void k_zero(int* __restrict__ p, int n) {
    int i = blockIdx.x * 256 + threadIdx.x;
    if (i < n) p[i] = 0;
}

// per-bucket edge histogram (no per-node work)
__global__ __launch_bounds__(256) void k_bhist(const int* __restrict__ col,
                                               int* __restrict__ bcnt) {
    __shared__ int hist[NBUK];
    const int tid = threadIdx.x;
    for (int i = tid; i < NBUK; i += 256) hist[i] = 0;
    __syncthreads();
    const int e0 = blockIdx.x * EPB;
    const int e1 = min(e0 + EPB, NE);
    for (int e = e0 + tid; e < e1; e += 256)
        atomicAdd(&hist[col[e] >> 9], 1);
    __syncthreads();
    for (int i = tid; i < NBUK; i += 256) {
        int h = hist[i];
        if (h) atomicAdd(&bcnt[i], h);
    }
}

// serial bucket scan; also terminal row_ptr entry
__global__ void k_bscan(const int* __restrict__ bcnt, int* __restrict__ bbase,
                        int* __restrict__ bcur, int* __restrict__ row_ptr) {
    if (threadIdx.x == 0 && blockIdx.x == 0) {
        int acc = 0;
        for (int i = 0; i < NBUK; ++i) { int t = bcnt[i]; bbase[i] = acc; bcur[i] = acc; acc += t; }
        bbase[NBUK] = acc;
        row_ptr[NN] = acc;
    }
}

// bin edges into bucket-grouped ebuf (packed r<<9 | c_local) via block reservations
__global__ __launch_bounds__(256) void k_bin(const int* __restrict__ row,
                                             const int* __restrict__ col,
                                             int* __restrict__ bcur,
                                             u32* __restrict__ ebuf) {
    __shared__ int hist[NBUK];
    const int tid = threadIdx.x;
    for (int i = tid; i < NBUK; i += 256) hist[i] = 0;
    __syncthreads();
    const int e0 = blockIdx.x * EPB;
    const int e1 = min(e0 + EPB, NE);
    for (int e = e0 + tid; e < e1; e += 256)
        atomicAdd(&hist[col[e] >> 9], 1);
    __syncthreads();
    for (int i = tid; i < NBUK; i += 256) {
        int c = hist[i];
        hist[i] = c ? atomicAdd(&bcur[i], c) : 0;
    }
    __syncthreads();
    for (int e = e0 + tid; e < e1; e += 256) {
        int c = col[e];
        int pos = atomicAdd(&hist[c >> 9], 1);
        ebuf[pos] = ((u32)row[e] << 9) | (u32)(c & 511);
    }
}

// one block per bucket: LDS count -> scan -> row_ptr/dis -> LDS-cursor scatter
__global__ __launch_bounds__(256) void k_bucket(const u32* __restrict__ ebuf,
                                                const int* __restrict__ bbase,
                                                int* __restrict__ row_ptr,
                                                float* __restrict__ dis,
                                                int* __restrict__ srcs) {
    __shared__ int lcnt[512];
    __shared__ int s[256];
    const int tid = threadIdx.x;
    const int b = blockIdx.x;
    const int base = bbase[b], end = bbase[b + 1];

    lcnt[tid] = 0; lcnt[tid + 256] = 0;
    __syncthreads();
    for (int i = base + tid; i < end; i += 256)
        atomicAdd(&lcnt[ebuf[i] & 511], 1);
    __syncthreads();

    // exclusive scan over 512 counts (2 per thread)
    const int c0 = lcnt[tid * 2], c1 = lcnt[tid * 2 + 1];
    s[tid] = c0 + c1;
    __syncthreads();
    for (int off = 1; off < 256; off <<= 1) {
        int t = 0;
        if (tid >= off) t = s[tid - off];
        __syncthreads();
        if (tid >= off) s[tid] += t;
        __syncthreads();
    }
    const int excl = (tid == 0) ? 0 : s[tid - 1];
    __syncthreads();
    lcnt[tid * 2] = excl;            // running cursors (bucket-local)
    lcnt[tid * 2 + 1] = excl + c0;

    const int v0 = b * 512 + tid * 2;
    if (v0 < NN) {
        row_ptr[v0] = base + excl;
        dis[v0] = rsqrtf((float)c0 + 1.0f);
    }
    if (v0 + 1 < NN) {
        row_ptr[v0 + 1] = base + excl + c0;
        dis[v0 + 1] = rsqrtf((float)c1 + 1.0f);
    }
    __syncthreads();

    for (int i = base + tid; i < end; i += 256) {
        u32 p = ebuf[i];
        int pos = atomicAdd(&lcnt[p & 511], 1);
        srcs[base + pos] = (int)(p >> 9);
    }
}

// ================= W pre-pack into MFMA B-fragment order (bf16) =================
// B elem = W[q*32 + (l>>4)*8 + j][t*16 + (l&15)]  stored at Wf[((t*4+q)*64+l)*8+j]
__global__ void k_packW2(const float* __restrict__ W1, const float* __restrict__ W2,
                         u16* __restrict__ Wf1, u16* __restrict__ Wf2) {
    int tid = blockIdx.x * 256 + threadIdx.x;
    if (tid >= 2048) return;
    int l = tid & 63;
    int tq = tid >> 6;
    int q = tq & 3, t = tq >> 2;
    int n = t * 16 + (l & 15);
    int k0 = q * 32 + (l >> 4) * 8;
    u32 p[4], r[4];
    for (int jj = 0; jj < 4; ++jj) {
        u16 lo1 = f2bf(W1[(size_t)(k0 + 2 * jj) * FD + n]);
        u16 hi1 = f2bf(W1[(size_t)(k0 + 2 * jj + 1) * FD + n]);
        p[jj] = (u32)lo1 | ((u32)hi1 << 16);
        u16 lo2 = f2bf(W2[(size_t)(k0 + 2 * jj) * FD + n]);
        u16 hi2 = f2bf(W2[(size_t)(k0 + 2 * jj + 1) * FD + n]);
        r[jj] = (u32)lo2 | ((u32)hi2 << 16);
    }
    *(uint4*)&Wf1[(size_t)tid * 8] = make_uint4(p[0], p[1], p[2], p[3]);
    *(uint4*)&Wf2[(size_t)tid * 8] = make_uint4(r[0], r[1], r[2], r[3]);
}

// ================= x f32 -> bf16 =================
__global__ void k_cvt(const float* __restrict__ x, u16* __restrict__ xb) {
    int i = blockIdx.x * 256 + threadIdx.x;     // 8 elems per thread
    const float4* s = (const float4*)x;
    float4 v0 = s[(size_t)i * 2];
    float4 v1 = s[(size_t)i * 2 + 1];
    uint4 p;
    p.x = (u32)f2bf(v0.x) | ((u32)f2bf(v0.y) << 16);
    p.y = (u32)f2bf(v0.z) | ((u32)f2bf(v0.w) << 16);
    p.z = (u32)f2bf(v1.x) | ((u32)f2bf(v1.y) << 16);
    p.w = (u32)f2bf(v1.z) | ((u32)f2bf(v1.w) << 16);
    ((uint4*)xb)[i] = p;
}

// ================= MFMA GEMM: out[r][f] = bf16( sum_k in[r][k] * W[k][f] ) =====
__global__ __launch_bounds__(256, 4) void k_gemm_mfma(const u16* __restrict__ in,
                                                      const u16* __restrict__ Wf,
                                                      u16* __restrict__ out) {
    __shared__ u16 Wl[16384];   // 32 KB packed fragments = 2048 uint4
    const int tid = threadIdx.x;
    {
        const uint4* s = (const uint4*)Wf;
        uint4* d = (uint4*)Wl;
#pragma unroll
        for (int i = 0; i < 8; ++i) d[tid + 256 * i] = s[tid + 256 * i];
    }
    __syncthreads();

    const int wave = tid >> 6, lane = tid & 63;
    const int gid = blockIdx.x * 4 + wave;
    if (gid >= NGROUP) return;
    const int row0 = gid * 16;
    const int lr = lane & 15;       // A row / D col
    const int lh = lane >> 4;       // k-subblock

    f32x4v acc[8];
#pragma unroll
    for (int t = 0; t < 8; ++t) { f32x4v z = {0.f, 0.f, 0.f, 0.f}; acc[t] = z; }

    const u16* arow = in + (size_t)(row0 + lr) * FD + lh * 8;
#pragma unroll
    for (int q = 0; q < 4; ++q) {
        bf16x8 a = *(const bf16x8*)(arow + q * 32);
#pragma unroll
        for (int t = 0; t < 8; ++t) {
            bf16x8 b = *(const bf16x8*)(&Wl[(size_t)(t * 4 + q) * 512 + lane * 8]);
            acc[t] = __builtin_amdgcn_mfma_f32_16x16x32_bf16(a, b, acc[t], 0, 0, 0);
        }
    }
#pragma unroll
    for (int t = 0; t < 8; ++t) {
#pragma unroll
        for (int j = 0; j < 4; ++j) {
            const int r = row0 + lh * 4 + j;
            out[(size_t)r * FD + t * 16 + lr] = f2bf(acc[t][j]);
        }
    }
}

// ================= aggregation by gather (bf16 payload, 16 lanes/node) =========
template <bool BF16OUT>
__global__ __launch_bounds__(256) void k_agg_gather(const u16* __restrict__ hb,
                                                    const float* __restrict__ b,
                                                    const float* __restrict__ dis,
                                                    const int* __restrict__ row_ptr,
                                                    const int* __restrict__ srcs,
                                                    void* __restrict__ outv) {
    const int v = (blockIdx.x * 256 + threadIdx.x) >> 4;
    if (v >= NN) return;
    const int f8 = threadIdx.x & 15;          // 8 features per thread
    const uint4* h4 = (const uint4*)hb;       // 16 uint4 per node row

    const float dv = dis[v];
    float4 aL = ((const float4*)b)[f8 * 2];
    float4 aH = ((const float4*)b)[f8 * 2 + 1];
    {
        const float sl = dv * dv;
        uint4 u = h4[(size_t)v * 16 + f8];
        acc8(aL, aH, sl, u);
    }

    int e = row_ptr[v];
    const int end = row_ptr[v + 1];
    for (; e + 3 < end; e += 4) {
        const int s0 = srcs[e], s1 = srcs[e + 1], s2 = srcs[e + 2], s3 = srcs[e + 3];
        const float w0 = dv * dis[s0];
        const float w1 = dv * dis[s1];
        const float w2 = dv * dis[s2];
        const float w3 = dv * dis[s3];
        const uint4 u0 = h4[(size_t)s0 * 16 + f8];
        const uint4 u1 = h4[(size_t)s1 * 16 + f8];
        const uint4 u2 = h4[(size_t)s2 * 16 + f8];
        const uint4 u3 = h4[(size_t)s3 * 16 + f8];
        acc8(aL, aH, w0, u0); acc8(aL, aH, w1, u1);
        acc8(aL, aH, w2, u2); acc8(aL, aH, w3, u3);
    }
    for (; e < end; ++e) {
        const int s0 = srcs[e];
        const float w0 = dv * dis[s0];
        const uint4 u0 = h4[(size_t)s0 * 16 + f8];
        acc8(aL, aH, w0, u0);
    }

    if (BF16OUT) {
        uint4 p;
        p.x = (u32)f2bf(fmaxf(aL.x, 0.f)) | ((u32)f2bf(fmaxf(aL.y, 0.f)) << 16);
        p.y = (u32)f2bf(fmaxf(aL.z, 0.f)) | ((u32)f2bf(fmaxf(aL.w, 0.f)) << 16);
        p.z = (u32)f2bf(fmaxf(aH.x, 0.f)) | ((u32)f2bf(fmaxf(aH.y, 0.f)) << 16);
        p.w = (u32)f2bf(fmaxf(aH.z, 0.f)) | ((u32)f2bf(fmaxf(aH.w, 0.f)) << 16);
        ((uint4*)outv)[(size_t)v * 16 + f8] = p;
    } else {
        float4* o = (float4*)outv;
        o[(size_t)v * 32 + f8 * 2] = aL;
        o[(size_t)v * 32 + f8 * 2 + 1] = aH;
    }
}

// ================= launch =================

extern "C" void kernel_launch(void* const* d_in, const int* in_sizes, int n_in,
                              void* d_out, int out_size, void* d_ws, size_t ws_size,
                              hipStream_t stream) {
    const float* x  = (const float*)d_in[0];
    const int*   ei = (const int*)d_in[1];
    const float* W1 = (const float*)d_in[2];
    const float* b1 = (const float*)d_in[3];
    const float* W2 = (const float*)d_in[4];
    const float* b2 = (const float*)d_in[5];
    float* out = (float*)d_out;

    const int* row = ei;        // source (gather side)
    const int* col = ei + NE;   // target (scatter side)

    // ---- workspace layout (256B-aligned regions) ----
    char* base = (char*)d_ws;
    size_t o = 0;
    auto take = [&](size_t bytes) -> void* {
        void* p = base + o;
        o += (bytes + 255) & ~(size_t)255;
        return p;
    };
    int*   row_ptr = (int*)take((size_t)(NN + 32) * 4);
    int*   bbase   = (int*)take(256 * 4);
    int*   bcur    = (int*)take(256 * 4);
    int*   bcnt    = (int*)take(256 * 4);
    float* dis     = (float*)take((size_t)NN * 4);
    u16*   Wf1     = (u16*)take(16384 * 2);
    u16*   Wf2     = (u16*)take(16384 * 2);
    u16*   hb      = (u16*)take((size_t)NN * FD * 2);
    u16*   aggb    = (u16*)take((size_t)NN * FD * 2);
    int*   srcs    = (int*)take((size_t)NE * 4);
    void*  alias   = take((size_t)NN * FD * 2);   // ebuf (6.4MB) then xb (25.6MB)
    u32*   ebuf    = (u32*)alias;
    u16*   xb      = (u16*)alias;

    // ---- CSC build (all per-node atomics in LDS) ----
    k_zero<<<1, 256, 0, stream>>>(bcnt, 256);
    k_bhist<<<NB_E, 256, 0, stream>>>(col, bcnt);
    k_bscan<<<1, 64, 0, stream>>>(bcnt, bbase, bcur, row_ptr);
    k_bin<<<NB_E, 256, 0, stream>>>(row, col, bcur, ebuf);
    k_bucket<<<NBUK, 256, 0, stream>>>(ebuf, bbase, row_ptr, dis, srcs);

    // ---- weights pack + x conversion (x overwrites dead ebuf) ----
    k_packW2<<<8, 256, 0, stream>>>(W1, W2, Wf1, Wf2);
    k_cvt<<<NGROUP, 256, 0, stream>>>(x, xb);

    // ---- layer 1 ----
    k_gemm_mfma<<<(NGROUP + 3) / 4, 256, 0, stream>>>(xb, Wf1, hb);
    k_agg_gather<true><<<NN * 16 / 256, 256, 0, stream>>>(hb, b1, dis, row_ptr, srcs, aggb);
    // ---- layer 2 ----
    k_gemm_mfma<<<(NGROUP + 3) / 4, 256, 0, stream>>>(aggb, Wf2, hb);
    k_agg_gather<false><<<NN * 16 / 256, 256, 0, stream>>>(hb, b2, dis, row_ptr, srcs, out);
}

// Round 9
// 240.722 us; speedup vs baseline: 23.4777x; 1.0195x over previous
//
#include <hip/hip_runtime.h>

#define NN 100000
#define NE 1600000
#define FD 128
#define NBUK 196            // ceil(NN / 512), bucket = col >> 9
#define EPB 2048            // edges per block in edge-pass kernels
#define NB_E 782            // ceil(NE / EPB)
#define NGROUP 6250         // NN/16 row-groups for MFMA gemm
#define NCHK 16             // src chunks of 8192 nodes (13 used)

typedef unsigned int  u32;
typedef unsigned short u16;
typedef __bf16 bf16x8 __attribute__((ext_vector_type(8)));
typedef float  f32x4v __attribute__((ext_vector_type(4)));

__device__ __forceinline__ u16 f2bf(float f) {
    u32 u = __float_as_uint(f);
    u32 r = (u + 0x7FFFu + ((u >> 16) & 1u)) >> 16;   // RNE
    return (u16)r;
}

__device__ __forceinline__ void acc2(float& x, float& y, float wt, u32 w) {
    x += wt * __uint_as_float(w << 16);
    y += wt * __uint_as_float(w & 0xffff0000u);
}
__device__ __forceinline__ void acc8(float4& L, float4& H, float wt, uint4 u) {
    acc2(L.x, L.y, wt, u.x); acc2(L.z, L.w, wt, u.y);
    acc2(H.x, H.y, wt, u.z); acc2(H.z, H.w, wt, u.w);
}

// ================= graph build (bucketed CSC, LDS-only per-node atomics) =======

__global__ void k_zero(int* __restrict__ p, int n) {
    int i = blockIdx.x * 256 + threadIdx.x;
    if (i < n) p[i] = 0;
}

// per-bucket edge histogram
__global__ __launch_bounds__(256) void k_bhist(const int* __restrict__ col,
                                               int* __restrict__ bcnt) {
    __shared__ int hist[NBUK];
    const int tid = threadIdx.x;
    for (int i = tid; i < NBUK; i += 256) hist[i] = 0;
    __syncthreads();
    const int e0 = blockIdx.x * EPB;
    const int e1 = min(e0 + EPB, NE);
    for (int e = e0 + tid; e < e1; e += 256)
        atomicAdd(&hist[col[e] >> 9], 1);
    __syncthreads();
    for (int i = tid; i < NBUK; i += 256) {
        int h = hist[i];
        if (h) atomicAdd(&bcnt[i], h);
    }
}

// serial bucket scan; also terminal row_ptr entry
__global__ void k_bscan(const int* __restrict__ bcnt, int* __restrict__ bbase,
                        int* __restrict__ bcur, int* __restrict__ row_ptr) {
    if (threadIdx.x == 0 && blockIdx.x == 0) {
        int acc = 0;
        for (int i = 0; i < NBUK; ++i) { int t = bcnt[i]; bbase[i] = acc; bcur[i] = acc; acc += t; }
        bbase[NBUK] = acc;
        row_ptr[NN] = acc;
    }
}

// bin edges into bucket-grouped ebuf (packed r<<9 | c_local) via block reservations
__global__ __launch_bounds__(256) void k_bin(const int* __restrict__ row,
                                             const int* __restrict__ col,
                                             int* __restrict__ bcur,
                                             u32* __restrict__ ebuf) {
    __shared__ int hist[NBUK];
    const int tid = threadIdx.x;
    for (int i = tid; i < NBUK; i += 256) hist[i] = 0;
    __syncthreads();
    const int e0 = blockIdx.x * EPB;
    const int e1 = min(e0 + EPB, NE);
    for (int e = e0 + tid; e < e1; e += 256)
        atomicAdd(&hist[col[e] >> 9], 1);
    __syncthreads();
    for (int i = tid; i < NBUK; i += 256) {
        int c = hist[i];
        hist[i] = c ? atomicAdd(&bcur[i], c) : 0;
    }
    __syncthreads();
    for (int e = e0 + tid; e < e1; e += 256) {
        int c = col[e];
        int pos = atomicAdd(&hist[c >> 9], 1);
        ebuf[pos] = ((u32)row[e] << 9) | (u32)(c & 511);
    }
}

// one block per bucket: per-(node,chunk) LDS counting sort -> row_ptr/dis -> scatter
// srcs within each node's segment end up sorted by src chunk (src>>13).
__global__ __launch_bounds__(256) void k_bucket(const u32* __restrict__ ebuf,
                                                const int* __restrict__ bbase,
                                                int* __restrict__ row_ptr,
                                                float* __restrict__ dis,
                                                int* __restrict__ srcs) {
    __shared__ int cnt[512 * NCHK];   // 32 KB
    __shared__ int s[256];
    const int tid = threadIdx.x;
    const int b = blockIdx.x;
    const int base = bbase[b], end = bbase[b + 1];

    for (int i = tid; i < 512 * NCHK; i += 256) cnt[i] = 0;
    __syncthreads();
    for (int i = base + tid; i < end; i += 256) {
        u32 p = ebuf[i];
        atomicAdd(&cnt[(p & 511) * NCHK + ((p >> 9) >> 13)], 1);
    }
    __syncthreads();

    // per-node totals (2 nodes per thread)
    int t0 = 0, t1 = 0;
#pragma unroll
    for (int c = 0; c < NCHK; ++c) {
        t0 += cnt[(tid * 2) * NCHK + c];
        t1 += cnt[(tid * 2 + 1) * NCHK + c];
    }
    s[tid] = t0 + t1;
    __syncthreads();
    for (int off = 1; off < 256; off <<= 1) {
        int t = 0;
        if (tid >= off) t = s[tid - off];
        __syncthreads();
        if (tid >= off) s[tid] += t;
        __syncthreads();
    }
    const int excl = (tid == 0) ? 0 : s[tid - 1];

    // convert counts -> bucket-local cursors (node-major, chunk-sorted)
    int cur0 = excl, cur1 = excl + t0;
#pragma unroll
    for (int c = 0; c < NCHK; ++c) {
        int i0 = (tid * 2) * NCHK + c;
        int v = cnt[i0]; cnt[i0] = cur0; cur0 += v;
        int i1 = (tid * 2 + 1) * NCHK + c;
        int w = cnt[i1]; cnt[i1] = cur1; cur1 += w;
    }

    const int v0 = b * 512 + tid * 2;
    if (v0 < NN) {
        row_ptr[v0] = base + excl;
        dis[v0] = rsqrtf((float)t0 + 1.0f);
    }
    if (v0 + 1 < NN) {
        row_ptr[v0 + 1] = base + excl + t0;
        dis[v0 + 1] = rsqrtf((float)t1 + 1.0f);
    }
    __syncthreads();

    for (int i = base + tid; i < end; i += 256) {
        u32 p = ebuf[i];
        int pos = atomicAdd(&cnt[(p & 511) * NCHK + ((p >> 9) >> 13)], 1);
        srcs[base + pos] = (int)(p >> 9);
    }
}

// ================= W pre-pack into MFMA B-fragment order (bf16) =================
// B elem = W[q*32 + (l>>4)*8 + j][t*16 + (l&15)]  stored at Wf[((t*4+q)*64+l)*8+j]
__global__ void k_packW2(const float* __restrict__ W1, const float* __restrict__ W2,
                         u16* __restrict__ Wf1, u16* __restrict__ Wf2) {
    int tid = blockIdx.x * 256 + threadIdx.x;
    if (tid >= 2048) return;
    int l = tid & 63;
    int tq = tid >> 6;
    int q = tq & 3, t = tq >> 2;
    int n = t * 16 + (l & 15);
    int k0 = q * 32 + (l >> 4) * 8;
    u32 p[4], r[4];
    for (int jj = 0; jj < 4; ++jj) {
        u16 lo1 = f2bf(W1[(size_t)(k0 + 2 * jj) * FD + n]);
        u16 hi1 = f2bf(W1[(size_t)(k0 + 2 * jj + 1) * FD + n]);
        p[jj] = (u32)lo1 | ((u32)hi1 << 16);
        u16 lo2 = f2bf(W2[(size_t)(k0 + 2 * jj) * FD + n]);
        u16 hi2 = f2bf(W2[(size_t)(k0 + 2 * jj + 1) * FD + n]);
        r[jj] = (u32)lo2 | ((u32)hi2 << 16);
    }
    *(uint4*)&Wf1[(size_t)tid * 8] = make_uint4(p[0], p[1], p[2], p[3]);
    *(uint4*)&Wf2[(size_t)tid * 8] = make_uint4(r[0], r[1], r[2], r[3]);
}

// ================= MFMA GEMM: out[r][f] = bf16( sum_k in[r][k] * W[k][f] ) =====
// F32IN: input rows are f32 (converted to bf16 in-register); else bf16.
template <bool F32IN>
__global__ __launch_bounds__(256, 4) void k_gemm_mfma(const void* __restrict__ inv,
                                                      const u16* __restrict__ Wf,
                                                      u16* __restrict__ out) {
    __shared__ u16 Wl[16384];   // 32 KB packed fragments = 2048 uint4
    const int tid = threadIdx.x;
    {
        const uint4* s = (const uint4*)Wf;
        uint4* d = (uint4*)Wl;
#pragma unroll
        for (int i = 0; i < 8; ++i) d[tid + 256 * i] = s[tid + 256 * i];
    }
    __syncthreads();

    const int wave = tid >> 6, lane = tid & 63;
    const int gid = blockIdx.x * 4 + wave;
    if (gid >= NGROUP) return;
    const int row0 = gid * 16;
    const int lr = lane & 15;       // A row / D col
    const int lh = lane >> 4;       // k-subblock

    f32x4v acc[8];
#pragma unroll
    for (int t = 0; t < 8; ++t) { f32x4v z = {0.f, 0.f, 0.f, 0.f}; acc[t] = z; }

#pragma unroll
    for (int q = 0; q < 4; ++q) {
        bf16x8 a;
        if (F32IN) {
            const float* arow = (const float*)inv + (size_t)(row0 + lr) * FD + lh * 8 + q * 32;
            float4 f0 = *(const float4*)(arow);
            float4 f1 = *(const float4*)(arow + 4);
            union { bf16x8 v; u16 s[8]; } ua;
            ua.s[0] = f2bf(f0.x); ua.s[1] = f2bf(f0.y);
            ua.s[2] = f2bf(f0.z); ua.s[3] = f2bf(f0.w);
            ua.s[4] = f2bf(f1.x); ua.s[5] = f2bf(f1.y);
            ua.s[6] = f2bf(f1.z); ua.s[7] = f2bf(f1.w);
            a = ua.v;
        } else {
            const u16* arow = (const u16*)inv + (size_t)(row0 + lr) * FD + lh * 8 + q * 32;
            a = *(const bf16x8*)arow;
        }
#pragma unroll
        for (int t = 0; t < 8; ++t) {
            bf16x8 bfr = *(const bf16x8*)(&Wl[(size_t)(t * 4 + q) * 512 + lane * 8]);
            acc[t] = __builtin_amdgcn_mfma_f32_16x16x32_bf16(a, bfr, acc[t], 0, 0, 0);
        }
    }
#pragma unroll
    for (int t = 0; t < 8; ++t) {
#pragma unroll
        for (int j = 0; j < 4; ++j) {
            const int r = row0 + lh * 4 + j;
            out[(size_t)r * FD + t * 16 + lr] = f2bf(acc[t][j]);
        }
    }
}

// ================= aggregation by gather (bf16 payload, 16 lanes/node) =========
template <bool BF16OUT>
__global__ __launch_bounds__(256) void k_agg_gather(const u16* __restrict__ hb,
                                                    const float* __restrict__ b,
                                                    const float* __restrict__ dis,
                                                    const int* __restrict__ row_ptr,
                                                    const int* __restrict__ srcs,
                                                    void* __restrict__ outv) {
    const int v = (blockIdx.x * 256 + threadIdx.x) >> 4;
    if (v >= NN) return;
    const int f8 = threadIdx.x & 15;          // 8 features per thread
    const uint4* h4 = (const uint4*)hb;       // 16 uint4 per node row

    const float dv = dis[v];
    float4 aL = ((const float4*)b)[f8 * 2];
    float4 aH = ((const float4*)b)[f8 * 2 + 1];
    {
        const float sl = dv * dv;
        uint4 u = h4[(size_t)v * 16 + f8];
        acc8(aL, aH, sl, u);
    }

    int e = row_ptr[v];
    const int end = row_ptr[v + 1];
    for (; e + 3 < end; e += 4) {
        const int s0 = srcs[e], s1 = srcs[e + 1], s2 = srcs[e + 2], s3 = srcs[e + 3];
        const float w0 = dv * dis[s0];
        const float w1 = dv * dis[s1];
        const float w2 = dv * dis[s2];
        const float w3 = dv * dis[s3];
        const uint4 u0 = h4[(size_t)s0 * 16 + f8];
        const uint4 u1 = h4[(size_t)s1 * 16 + f8];
        const uint4 u2 = h4[(size_t)s2 * 16 + f8];
        const uint4 u3 = h4[(size_t)s3 * 16 + f8];
        acc8(aL, aH, w0, u0); acc8(aL, aH, w1, u1);
        acc8(aL, aH, w2, u2); acc8(aL, aH, w3, u3);
    }
    for (; e < end; ++e) {
        const int s0 = srcs[e];
        const float w0 = dv * dis[s0];
        const uint4 u0 = h4[(size_t)s0 * 16 + f8];
        acc8(aL, aH, w0, u0);
    }

    if (BF16OUT) {
        uint4 p;
        p.x = (u32)f2bf(fmaxf(aL.x, 0.f)) | ((u32)f2bf(fmaxf(aL.y, 0.f)) << 16);
        p.y = (u32)f2bf(fmaxf(aL.z, 0.f)) | ((u32)f2bf(fmaxf(aL.w, 0.f)) << 16);
        p.z = (u32)f2bf(fmaxf(aH.x, 0.f)) | ((u32)f2bf(fmaxf(aH.y, 0.f)) << 16);
        p.w = (u32)f2bf(fmaxf(aH.z, 0.f)) | ((u32)f2bf(fmaxf(aH.w, 0.f)) << 16);
        ((uint4*)outv)[(size_t)v * 16 + f8] = p;
    } else {
        float4* o = (float4*)outv;
        o[(size_t)v * 32 + f8 * 2] = aL;
        o[(size_t)v * 32 + f8 * 2 + 1] = aH;
    }
}

// ================= launch =================

extern "C" void kernel_launch(void* const* d_in, const int* in_sizes, int n_in,
                              void* d_out, int out_size, void* d_ws, size_t ws_size,
                              hipStream_t stream) {
    const float* x  = (const float*)d_in[0];
    const int*   ei = (const int*)d_in[1];
    const float* W1 = (const float*)d_in[2];
    const float* b1 = (const float*)d_in[3];
    const float* W2 = (const float*)d_in[4];
    const float* b2 = (const float*)d_in[5];
    float* out = (float*)d_out;

    const int* row = ei;        // source (gather side)
    const int* col = ei + NE;   // target (scatter side)

    // ---- workspace layout (256B-aligned regions) ----
    char* base = (char*)d_ws;
    size_t o = 0;
    auto take = [&](size_t bytes) -> void* {
        void* p = base + o;
        o += (bytes + 255) & ~(size_t)255;
        return p;
    };
    int*   row_ptr = (int*)take((size_t)(NN + 32) * 4);
    int*   bbase   = (int*)take(256 * 4);
    int*   bcur    = (int*)take(256 * 4);
    int*   bcnt    = (int*)take(256 * 4);
    float* dis     = (float*)take((size_t)NN * 4);
    u16*   Wf1     = (u16*)take(16384 * 2);
    u16*   Wf2     = (u16*)take(16384 * 2);
    u16*   hb      = (u16*)take((size_t)NN * FD * 2);
    u16*   aggb    = (u16*)take((size_t)NN * FD * 2);
    int*   srcs    = (int*)take((size_t)NE * 4);
    u32*   ebuf    = (u32*)take((size_t)NE * 4);

    // ---- CSC build (all per-node atomics in LDS; chunk-sorted adjacency) ----
    k_zero<<<1, 256, 0, stream>>>(bcnt, 256);
    k_bhist<<<NB_E, 256, 0, stream>>>(col, bcnt);
    k_bscan<<<1, 64, 0, stream>>>(bcnt, bbase, bcur, row_ptr);
    k_bin<<<NB_E, 256, 0, stream>>>(row, col, bcur, ebuf);
    k_bucket<<<NBUK, 256, 0, stream>>>(ebuf, bbase, row_ptr, dis, srcs);

    // ---- weights pack ----
    k_packW2<<<8, 256, 0, stream>>>(W1, W2, Wf1, Wf2);

    // ---- layer 1 (f32 input converted in-kernel) ----
    k_gemm_mfma<true><<<(NGROUP + 3) / 4, 256, 0, stream>>>(x, Wf1, hb);
    k_agg_gather<true><<<NN * 16 / 256, 256, 0, stream>>>(hb, b1, dis, row_ptr, srcs, aggb);
    // ---- layer 2 ----
    k_gemm_mfma<false><<<(NGROUP + 3) / 4, 256, 0, stream>>>(aggb, Wf2, hb);
    k_agg_gather<false><<<NN * 16 / 256, 256, 0, stream>>>(hb, b2, dis, row_ptr, srcs, out);
}

// Round 10
// 229.675 us; speedup vs baseline: 24.6070x; 1.0481x over previous
//
#include <hip/hip_runtime.h>

#define NN 100000
#define NE 1600000
#define FD 128
#define NBUK 196            // ceil(NN / 512), bucket = col >> 9
#define BCAP 9216           // fixed slots per bucket (mean 8192, +11 sigma)
#define EPBB 8192           // edges per block in k_bin
#define NBB 196             // ceil(NE / EPBB)
#define NGROUP 6250         // NN/16 row-groups for MFMA gemm

typedef unsigned int  u32;
typedef unsigned short u16;
typedef __bf16 bf16x8 __attribute__((ext_vector_type(8)));
typedef float  f32x4v __attribute__((ext_vector_type(4)));

__device__ __forceinline__ u16 f2bf(float f) {
    u32 u = __float_as_uint(f);
    u32 r = (u + 0x7FFFu + ((u >> 16) & 1u)) >> 16;   // RNE
    return (u16)r;
}

__device__ __forceinline__ void acc2(float& x, float& y, float wt, u32 w) {
    x += wt * __uint_as_float(w << 16);
    y += wt * __uint_as_float(w & 0xffff0000u);
}
__device__ __forceinline__ void acc8(float4& L, float4& H, float wt, uint4 u) {
    acc2(L.x, L.y, wt, u.x); acc2(L.z, L.w, wt, u.y);
    acc2(H.x, H.y, wt, u.z); acc2(H.z, H.w, wt, u.w);
}

// ================= graph build =================

// init fixed bucket cursors
__global__ void k_binit(int* __restrict__ bcur) {
    int i = threadIdx.x;
    if (i < NBUK) bcur[i] = i * BCAP;
}

// bin edges into fixed-capacity bucket regions (packed r<<9 | c_local)
__global__ __launch_bounds__(256) void k_bin(const int* __restrict__ row,
                                             const int* __restrict__ col,
                                             int* __restrict__ bcur,
                                             u32* __restrict__ ebuf) {
    __shared__ int hist[NBUK];
    const int tid = threadIdx.x;
    for (int i = tid; i < NBUK; i += 256) hist[i] = 0;
    __syncthreads();
    const int e0 = blockIdx.x * EPBB;
    const int e1 = min(e0 + EPBB, NE);
    for (int e = e0 + tid; e < e1; e += 256)
        atomicAdd(&hist[col[e] >> 9], 1);
    __syncthreads();
    for (int i = tid; i < NBUK; i += 256) {
        int c = hist[i];
        hist[i] = c ? atomicAdd(&bcur[i], c) : 0;
    }
    __syncthreads();
    for (int e = e0 + tid; e < e1; e += 256) {
        int c = col[e];
        int pos = atomicAdd(&hist[c >> 9], 1);
        ebuf[pos] = ((u32)row[e] << 9) | (u32)(c & 511);
    }
}

// one block per bucket: LDS count -> scan -> nstart/ndeg/dis -> LDS-cursor scatter
__global__ __launch_bounds__(256) void k_bucket(const u32* __restrict__ ebuf,
                                                const int* __restrict__ bcur,
                                                int* __restrict__ nstart,
                                                int* __restrict__ ndeg,
                                                float* __restrict__ dis,
                                                int* __restrict__ srcs) {
    __shared__ int lcnt[512];
    __shared__ int s[256];
    const int tid = threadIdx.x;
    const int b = blockIdx.x;
    const int base = b * BCAP;
    const int end = bcur[b];            // base + actual count

    lcnt[tid] = 0; lcnt[tid + 256] = 0;
    __syncthreads();
    for (int i = base + tid; i < end; i += 256)
        atomicAdd(&lcnt[ebuf[i] & 511], 1);
    __syncthreads();

    const int c0 = lcnt[tid * 2], c1 = lcnt[tid * 2 + 1];
    s[tid] = c0 + c1;
    __syncthreads();
    for (int off = 1; off < 256; off <<= 1) {
        int t = 0;
        if (tid >= off) t = s[tid - off];
        __syncthreads();
        if (tid >= off) s[tid] += t;
        __syncthreads();
    }
    const int excl = (tid == 0) ? 0 : s[tid - 1];
    __syncthreads();
    lcnt[tid * 2] = excl;               // running bucket-local cursors
    lcnt[tid * 2 + 1] = excl + c0;

    const int v0 = b * 512 + tid * 2;
    if (v0 < NN) {
        nstart[v0] = base + excl;
        ndeg[v0] = c0;
        dis[v0] = rsqrtf((float)c0 + 1.0f);
    }
    if (v0 + 1 < NN) {
        nstart[v0 + 1] = base + excl + c0;
        ndeg[v0 + 1] = c1;
        dis[v0 + 1] = rsqrtf((float)c1 + 1.0f);
    }
    __syncthreads();

    for (int i = base + tid; i < end; i += 256) {
        u32 p = ebuf[i];
        int pos = atomicAdd(&lcnt[p & 511], 1);
        srcs[base + pos] = (int)(p >> 9);
    }
}

// per-edge (src, w = dis[dst]*dis[src]) table
__global__ __launch_bounds__(256) void k_wts(const int* __restrict__ nstart,
                                             const int* __restrict__ ndeg,
                                             const float* __restrict__ dis,
                                             const int* __restrict__ srcs,
                                             int2* __restrict__ ew) {
    const int v = (blockIdx.x * 256 + threadIdx.x) >> 4;
    if (v >= NN) return;
    const int l = threadIdx.x & 15;
    const float dv = dis[v];
    const int s0 = nstart[v], d = ndeg[v];
    for (int e = s0 + l; e < s0 + d; e += 16) {
        int s = srcs[e];
        ew[e] = make_int2(s, __float_as_int(dv * dis[s]));
    }
}

// ================= W pre-pack into MFMA B-fragment order (bf16) =================
// B elem = W[q*32 + (l>>4)*8 + j][t*16 + (l&15)]  stored at Wf[((t*4+q)*64+l)*8+j]
__global__ void k_packW2(const float* __restrict__ W1, const float* __restrict__ W2,
                         u16* __restrict__ Wf1, u16* __restrict__ Wf2) {
    int tid = blockIdx.x * 256 + threadIdx.x;
    if (tid >= 2048) return;
    int l = tid & 63;
    int tq = tid >> 6;
    int q = tq & 3, t = tq >> 2;
    int n = t * 16 + (l & 15);
    int k0 = q * 32 + (l >> 4) * 8;
    u32 p[4], r[4];
    for (int jj = 0; jj < 4; ++jj) {
        u16 lo1 = f2bf(W1[(size_t)(k0 + 2 * jj) * FD + n]);
        u16 hi1 = f2bf(W1[(size_t)(k0 + 2 * jj + 1) * FD + n]);
        p[jj] = (u32)lo1 | ((u32)hi1 << 16);
        u16 lo2 = f2bf(W2[(size_t)(k0 + 2 * jj) * FD + n]);
        u16 hi2 = f2bf(W2[(size_t)(k0 + 2 * jj + 1) * FD + n]);
        r[jj] = (u32)lo2 | ((u32)hi2 << 16);
    }
    *(uint4*)&Wf1[(size_t)tid * 8] = make_uint4(p[0], p[1], p[2], p[3]);
    *(uint4*)&Wf2[(size_t)tid * 8] = make_uint4(r[0], r[1], r[2], r[3]);
}

// ================= MFMA GEMM: out[r][f] = bf16( sum_k in[r][k] * W[k][f] ) =====
template <bool F32IN>
__global__ __launch_bounds__(256, 4) void k_gemm_mfma(const void* __restrict__ inv,
                                                      const u16* __restrict__ Wf,
                                                      u16* __restrict__ out) {
    __shared__ u16 Wl[16384];   // 32 KB packed fragments = 2048 uint4
    const int tid = threadIdx.x;
    {
        const uint4* s = (const uint4*)Wf;
        uint4* d = (uint4*)Wl;
#pragma unroll
        for (int i = 0; i < 8; ++i) d[tid + 256 * i] = s[tid + 256 * i];
    }
    __syncthreads();

    const int wave = tid >> 6, lane = tid & 63;
    const int gid = blockIdx.x * 4 + wave;
    if (gid >= NGROUP) return;
    const int row0 = gid * 16;
    const int lr = lane & 15;       // A row / D col
    const int lh = lane >> 4;       // k-subblock

    f32x4v acc[8];
#pragma unroll
    for (int t = 0; t < 8; ++t) { f32x4v z = {0.f, 0.f, 0.f, 0.f}; acc[t] = z; }

#pragma unroll
    for (int q = 0; q < 4; ++q) {
        bf16x8 a;
        if (F32IN) {
            const float* arow = (const float*)inv + (size_t)(row0 + lr) * FD + lh * 8 + q * 32;
            float4 f0 = *(const float4*)(arow);
            float4 f1 = *(const float4*)(arow + 4);
            union { bf16x8 v; u16 s[8]; } ua;
            ua.s[0] = f2bf(f0.x); ua.s[1] = f2bf(f0.y);
            ua.s[2] = f2bf(f0.z); ua.s[3] = f2bf(f0.w);
            ua.s[4] = f2bf(f1.x); ua.s[5] = f2bf(f1.y);
            ua.s[6] = f2bf(f1.z); ua.s[7] = f2bf(f1.w);
            a = ua.v;
        } else {
            const u16* arow = (const u16*)inv + (size_t)(row0 + lr) * FD + lh * 8 + q * 32;
            a = *(const bf16x8*)arow;
        }
#pragma unroll
        for (int t = 0; t < 8; ++t) {
            bf16x8 bfr = *(const bf16x8*)(&Wl[(size_t)(t * 4 + q) * 512 + lane * 8]);
            acc[t] = __builtin_amdgcn_mfma_f32_16x16x32_bf16(a, bfr, acc[t], 0, 0, 0);
        }
    }
#pragma unroll
    for (int t = 0; t < 8; ++t) {
#pragma unroll
        for (int j = 0; j < 4; ++j) {
            const int r = row0 + lh * 4 + j;
            out[(size_t)r * FD + t * 16 + lr] = f2bf(acc[t][j]);
        }
    }
}

// ================= aggregation by gather (bf16 payload, precomputed edge wts) ==
template <bool BF16OUT>
__global__ __launch_bounds__(256) void k_agg_gather(const u16* __restrict__ hb,
                                                    const float* __restrict__ b,
                                                    const float* __restrict__ dis,
                                                    const int* __restrict__ nstart,
                                                    const int* __restrict__ ndeg,
                                                    const int2* __restrict__ ew,
                                                    void* __restrict__ outv) {
    const int v = (blockIdx.x * 256 + threadIdx.x) >> 4;
    if (v >= NN) return;
    const int f8 = threadIdx.x & 15;          // 8 features per thread
    const uint4* h4 = (const uint4*)hb;       // 16 uint4 per node row

    const float dv = dis[v];
    float4 aL = ((const float4*)b)[f8 * 2];
    float4 aH = ((const float4*)b)[f8 * 2 + 1];
    {
        const float sl = dv * dv;
        uint4 u = h4[(size_t)v * 16 + f8];
        acc8(aL, aH, sl, u);
    }

    int e = nstart[v];
    const int end = e + ndeg[v];
    for (; e + 3 < end; e += 4) {
        const int2 p0 = ew[e], p1 = ew[e + 1], p2 = ew[e + 2], p3 = ew[e + 3];
        const uint4 u0 = h4[(size_t)p0.x * 16 + f8];
        const uint4 u1 = h4[(size_t)p1.x * 16 + f8];
        const uint4 u2 = h4[(size_t)p2.x * 16 + f8];
        const uint4 u3 = h4[(size_t)p3.x * 16 + f8];
        acc8(aL, aH, __int_as_float(p0.y), u0);
        acc8(aL, aH, __int_as_float(p1.y), u1);
        acc8(aL, aH, __int_as_float(p2.y), u2);
        acc8(aL, aH, __int_as_float(p3.y), u3);
    }
    for (; e < end; ++e) {
        const int2 p0 = ew[e];
        const uint4 u0 = h4[(size_t)p0.x * 16 + f8];
        acc8(aL, aH, __int_as_float(p0.y), u0);
    }

    if (BF16OUT) {
        uint4 p;
        p.x = (u32)f2bf(fmaxf(aL.x, 0.f)) | ((u32)f2bf(fmaxf(aL.y, 0.f)) << 16);
        p.y = (u32)f2bf(fmaxf(aL.z, 0.f)) | ((u32)f2bf(fmaxf(aL.w, 0.f)) << 16);
        p.z = (u32)f2bf(fmaxf(aH.x, 0.f)) | ((u32)f2bf(fmaxf(aH.y, 0.f)) << 16);
        p.w = (u32)f2bf(fmaxf(aH.z, 0.f)) | ((u32)f2bf(fmaxf(aH.w, 0.f)) << 16);
        ((uint4*)outv)[(size_t)v * 16 + f8] = p;
    } else {
        float4* o = (float4*)outv;
        o[(size_t)v * 32 + f8 * 2] = aL;
        o[(size_t)v * 32 + f8 * 2 + 1] = aH;
    }
}

// ================= launch =================

extern "C" void kernel_launch(void* const* d_in, const int* in_sizes, int n_in,
                              void* d_out, int out_size, void* d_ws, size_t ws_size,
                              hipStream_t stream) {
    const float* x  = (const float*)d_in[0];
    const int*   ei = (const int*)d_in[1];
    const float* W1 = (const float*)d_in[2];
    const float* b1 = (const float*)d_in[3];
    const float* W2 = (const float*)d_in[4];
    const float* b2 = (const float*)d_in[5];
    float* out = (float*)d_out;

    const int* row = ei;        // source (gather side)
    const int* col = ei + NE;   // target (scatter side)

    // ---- workspace layout (256B-aligned regions) ----
    char* base = (char*)d_ws;
    size_t o = 0;
    auto take = [&](size_t bytes) -> void* {
        void* p = base + o;
        o += (bytes + 255) & ~(size_t)255;
        return p;
    };
    int*   nstart  = (int*)take((size_t)NN * 4);
    int*   ndeg    = (int*)take((size_t)NN * 4);
    int*   bcur    = (int*)take(256 * 4);
    float* dis     = (float*)take((size_t)NN * 4);
    u16*   Wf1     = (u16*)take(16384 * 2);
    u16*   Wf2     = (u16*)take(16384 * 2);
    u16*   hb      = (u16*)take((size_t)NN * FD * 2);
    u16*   aggb    = (u16*)take((size_t)NN * FD * 2);
    int*   srcs    = (int*)take((size_t)NBUK * BCAP * 4);
    int2*  ew      = (int2*)take((size_t)NBUK * BCAP * 8);
    u32*   ebuf    = (u32*)take((size_t)NBUK * BCAP * 4);

    // ---- CSC build (fixed-capacity buckets, LDS-only per-node atomics) ----
    k_binit<<<1, 256, 0, stream>>>(bcur);
    k_bin<<<NBB, 256, 0, stream>>>(row, col, bcur, ebuf);
    k_bucket<<<NBUK, 256, 0, stream>>>(ebuf, bcur, nstart, ndeg, dis, srcs);
    k_wts<<<NGROUP, 256, 0, stream>>>(nstart, ndeg, dis, srcs, ew);

    // ---- weights pack ----
    k_packW2<<<8, 256, 0, stream>>>(W1, W2, Wf1, Wf2);

    // ---- layer 1 (f32 input converted in-kernel) ----
    k_gemm_mfma<true><<<(NGROUP + 3) / 4, 256, 0, stream>>>(x, Wf1, hb);
    k_agg_gather<true><<<NN * 16 / 256, 256, 0, stream>>>(hb, b1, dis, nstart, ndeg, ew, aggb);
    // ---- layer 2 ----
    k_gemm_mfma<false><<<(NGROUP + 3) / 4, 256, 0, stream>>>(aggb, Wf2, hb);
    k_agg_gather<false><<<NN * 16 / 256, 256, 0, stream>>>(hb, b2, dis, nstart, ndeg, ew, out);
}

// Round 11
// 198.631 us; speedup vs baseline: 28.4528x; 1.1563x over previous
//
#include <hip/hip_runtime.h>

#define NN 100000
#define NE 1600000
#define FD 128
#define NBUK 196            // ceil(NN / 512), bucket = col >> 9
#define BCAP 9216           // fixed slots per bucket (mean 8163, +11 sigma)
#define EPBB 8192           // edges per block in k_bin
#define NBB 196             // ceil(NE / EPBB)
#define NGROUP 6250         // NN/16 row-groups for MFMA gemm
#define GEMM_BLKS 1563      // ceil(NGROUP / 4)

typedef unsigned int  u32;
typedef unsigned short u16;
typedef __bf16 bf16x8 __attribute__((ext_vector_type(8)));
typedef float  f32x4v __attribute__((ext_vector_type(4)));

__device__ __forceinline__ u16 f2bf(float f) {
    u32 u = __float_as_uint(f);
    u32 r = (u + 0x7FFFu + ((u >> 16) & 1u)) >> 16;   // RNE
    return (u16)r;
}

__device__ __forceinline__ void acc2(float& x, float& y, float wt, u32 w) {
    x += wt * __uint_as_float(w << 16);
    y += wt * __uint_as_float(w & 0xffff0000u);
}
__device__ __forceinline__ void acc8(float4& L, float4& H, float wt, uint4 u) {
    acc2(L.x, L.y, wt, u.x); acc2(L.z, L.w, wt, u.y);
    acc2(H.x, H.y, wt, u.z); acc2(H.z, H.w, wt, u.w);
}

// ============ init bucket cursors + pack W1/W2 into MFMA B-fragment order ======
// B elem = W[q*32 + (l>>4)*8 + j][t*16 + (l&15)]  stored at Wf[((t*4+q)*64+l)*8+j]
__global__ void k_init_pack(int* __restrict__ bcur,
                            const float* __restrict__ W1, const float* __restrict__ W2,
                            u16* __restrict__ Wf1, u16* __restrict__ Wf2) {
    if (blockIdx.x == 0) {
        if (threadIdx.x < NBUK) bcur[threadIdx.x] = threadIdx.x * BCAP;
        return;
    }
    int tid = (blockIdx.x - 1) * 256 + threadIdx.x;   // 0..2047
    if (tid >= 2048) return;
    int l = tid & 63;
    int tq = tid >> 6;
    int q = tq & 3, t = tq >> 2;
    int n = t * 16 + (l & 15);
    int k0 = q * 32 + (l >> 4) * 8;
    u32 p[4], r[4];
    for (int jj = 0; jj < 4; ++jj) {
        u16 lo1 = f2bf(W1[(size_t)(k0 + 2 * jj) * FD + n]);
        u16 hi1 = f2bf(W1[(size_t)(k0 + 2 * jj + 1) * FD + n]);
        p[jj] = (u32)lo1 | ((u32)hi1 << 16);
        u16 lo2 = f2bf(W2[(size_t)(k0 + 2 * jj) * FD + n]);
        u16 hi2 = f2bf(W2[(size_t)(k0 + 2 * jj + 1) * FD + n]);
        r[jj] = (u32)lo2 | ((u32)hi2 << 16);
    }
    *(uint4*)&Wf1[(size_t)tid * 8] = make_uint4(p[0], p[1], p[2], p[3]);
    *(uint4*)&Wf2[(size_t)tid * 8] = make_uint4(r[0], r[1], r[2], r[3]);
}

// ============ mega: blocks [0,NBB) bin edges; blocks [NBB,..) GEMM-1 ===========
__global__ __launch_bounds__(256, 4) void k_mega(const int* __restrict__ row,
                                                 const int* __restrict__ col,
                                                 int* __restrict__ bcur,
                                                 u32* __restrict__ ebuf,
                                                 const float* __restrict__ x,
                                                 const u16* __restrict__ Wf1,
                                                 u16* __restrict__ hb) {
    __shared__ u16 smem[16384];     // 32 KB: bin uses first 784 B as hist; gemm as Wl
    const int tid = threadIdx.x;

    if (blockIdx.x < NBB) {
        // ---- bin edges into fixed-capacity bucket regions ----
        int* hist = (int*)smem;
        for (int i = tid; i < NBUK; i += 256) hist[i] = 0;
        __syncthreads();
        const int e0 = blockIdx.x * EPBB;
        const int e1 = min(e0 + EPBB, NE);
        for (int e = e0 + tid; e < e1; e += 256)
            atomicAdd(&hist[col[e] >> 9], 1);
        __syncthreads();
        for (int i = tid; i < NBUK; i += 256) {
            int c = hist[i];
            hist[i] = c ? atomicAdd(&bcur[i], c) : 0;
        }
        __syncthreads();
        for (int e = e0 + tid; e < e1; e += 256) {
            int c = col[e];
            int pos = atomicAdd(&hist[c >> 9], 1);
            ebuf[pos] = ((u32)row[e] << 9) | (u32)(c & 511);
        }
        return;
    }

    // ---- GEMM-1: hb[r][f] = bf16( sum_k bf16(x[r][k]) * W1[k][f] ) ----
    {
        const uint4* s = (const uint4*)Wf1;
        uint4* d = (uint4*)smem;
#pragma unroll
        for (int i = 0; i < 8; ++i) d[tid + 256 * i] = s[tid + 256 * i];
    }
    __syncthreads();

    const int wave = tid >> 6, lane = tid & 63;
    const int gid = (blockIdx.x - NBB) * 4 + wave;
    if (gid >= NGROUP) return;
    const int row0 = gid * 16;
    const int lr = lane & 15;
    const int lh = lane >> 4;

    f32x4v acc[8];
#pragma unroll
    for (int t = 0; t < 8; ++t) { f32x4v z = {0.f, 0.f, 0.f, 0.f}; acc[t] = z; }

#pragma unroll
    for (int q = 0; q < 4; ++q) {
        const float* arow = x + (size_t)(row0 + lr) * FD + lh * 8 + q * 32;
        float4 f0 = *(const float4*)(arow);
        float4 f1 = *(const float4*)(arow + 4);
        union { bf16x8 v; u16 s[8]; } ua;
        ua.s[0] = f2bf(f0.x); ua.s[1] = f2bf(f0.y);
        ua.s[2] = f2bf(f0.z); ua.s[3] = f2bf(f0.w);
        ua.s[4] = f2bf(f1.x); ua.s[5] = f2bf(f1.y);
        ua.s[6] = f2bf(f1.z); ua.s[7] = f2bf(f1.w);
        bf16x8 a = ua.v;
#pragma unroll
        for (int t = 0; t < 8; ++t) {
            bf16x8 bfr = *(const bf16x8*)(&smem[(size_t)(t * 4 + q) * 512 + lane * 8]);
            acc[t] = __builtin_amdgcn_mfma_f32_16x16x32_bf16(a, bfr, acc[t], 0, 0, 0);
        }
    }
#pragma unroll
    for (int t = 0; t < 8; ++t) {
#pragma unroll
        for (int j = 0; j < 4; ++j) {
            const int r = row0 + lh * 4 + j;
            hb[(size_t)r * FD + t * 16 + lr] = f2bf(acc[t][j]);
        }
    }
}

// ============ one block per bucket: count -> scan -> nstart/ndeg/dis -> scatter =
__global__ __launch_bounds__(256) void k_bucket(const u32* __restrict__ ebuf,
                                                const int* __restrict__ bcur,
                                                int* __restrict__ nstart,
                                                int* __restrict__ ndeg,
                                                float* __restrict__ dis,
                                                int* __restrict__ srcs) {
    __shared__ int lcnt[512];
    __shared__ int s[256];
    const int tid = threadIdx.x;
    const int b = blockIdx.x;
    const int base = b * BCAP;
    const int end = bcur[b];            // base + actual count

    lcnt[tid] = 0; lcnt[tid + 256] = 0;
    __syncthreads();
    for (int i = base + tid; i < end; i += 256)
        atomicAdd(&lcnt[ebuf[i] & 511], 1);
    __syncthreads();

    const int c0 = lcnt[tid * 2], c1 = lcnt[tid * 2 + 1];
    s[tid] = c0 + c1;
    __syncthreads();
    for (int off = 1; off < 256; off <<= 1) {
        int t = 0;
        if (tid >= off) t = s[tid - off];
        __syncthreads();
        if (tid >= off) s[tid] += t;
        __syncthreads();
    }
    const int excl = (tid == 0) ? 0 : s[tid - 1];
    __syncthreads();
    lcnt[tid * 2] = excl;
    lcnt[tid * 2 + 1] = excl + c0;

    const int v0 = b * 512 + tid * 2;
    if (v0 < NN) {
        nstart[v0] = base + excl;
        ndeg[v0] = c0;
        dis[v0] = rsqrtf((float)c0 + 1.0f);
    }
    if (v0 + 1 < NN) {
        nstart[v0 + 1] = base + excl + c0;
        ndeg[v0 + 1] = c1;
        dis[v0 + 1] = rsqrtf((float)c1 + 1.0f);
    }
    __syncthreads();

    for (int i = base + tid; i < end; i += 256) {
        u32 p = ebuf[i];
        int pos = atomicAdd(&lcnt[p & 511], 1);
        srcs[base + pos] = (int)(p >> 9);
    }
}

// ============ fused: gather-1 + bias + ReLU + GEMM-2 -> hb2 (bf16) =============
// block = 16 dst nodes; LDS 16x128 bf16 tile (row stride 272 B); 4 waves x 2 n-tiles
__global__ __launch_bounds__(256) void k_agg2(const u16* __restrict__ hb,
                                              const float* __restrict__ b1,
                                              const float* __restrict__ dis,
                                              const int* __restrict__ nstart,
                                              const int* __restrict__ ndeg,
                                              const int* __restrict__ srcs,
                                              const u16* __restrict__ Wf2,
                                              u16* __restrict__ hb2) {
    __shared__ u16 tile[16 * 136];      // 4352 B
    const int tid = threadIdx.x;
    const int nl = tid >> 4;            // node-local 0..15
    const int f8 = tid & 15;            // 8-feature slice
    const int v = blockIdx.x * 16 + nl; // always < NN (6250*16 = NN)
    const uint4* h4 = (const uint4*)hb;

    const float dv = dis[v];
    float4 aL = ((const float4*)b1)[f8 * 2];
    float4 aH = ((const float4*)b1)[f8 * 2 + 1];
    {
        const float sl = dv * dv;
        uint4 u = h4[(size_t)v * 16 + f8];
        acc8(aL, aH, sl, u);
    }

    int e = nstart[v];
    const int end = e + ndeg[v];
    for (; e + 3 < end; e += 4) {
        const int s0 = srcs[e], s1 = srcs[e + 1], s2 = srcs[e + 2], s3 = srcs[e + 3];
        const float w0 = dv * dis[s0];
        const float w1 = dv * dis[s1];
        const float w2 = dv * dis[s2];
        const float w3 = dv * dis[s3];
        const uint4 u0 = h4[(size_t)s0 * 16 + f8];
        const uint4 u1 = h4[(size_t)s1 * 16 + f8];
        const uint4 u2 = h4[(size_t)s2 * 16 + f8];
        const uint4 u3 = h4[(size_t)s3 * 16 + f8];
        acc8(aL, aH, w0, u0); acc8(aL, aH, w1, u1);
        acc8(aL, aH, w2, u2); acc8(aL, aH, w3, u3);
    }
    for (; e < end; ++e) {
        const int s0 = srcs[e];
        const float w0 = dv * dis[s0];
        const uint4 u0 = h4[(size_t)s0 * 16 + f8];
        acc8(aL, aH, w0, u0);
    }

    // ReLU + bf16 pack -> LDS tile row nl, features f8*8..+8
    {
        uint4 p;
        p.x = (u32)f2bf(fmaxf(aL.x, 0.f)) | ((u32)f2bf(fmaxf(aL.y, 0.f)) << 16);
        p.y = (u32)f2bf(fmaxf(aL.z, 0.f)) | ((u32)f2bf(fmaxf(aL.w, 0.f)) << 16);
        p.z = (u32)f2bf(fmaxf(aH.x, 0.f)) | ((u32)f2bf(fmaxf(aH.y, 0.f)) << 16);
        p.w = (u32)f2bf(fmaxf(aH.z, 0.f)) | ((u32)f2bf(fmaxf(aH.w, 0.f)) << 16);
        *(uint4*)&tile[nl * 136 + f8 * 8] = p;
    }
    __syncthreads();

    // GEMM-2 on the 16-row tile: wave w owns n-tiles 2w, 2w+1
    const int wave = tid >> 6, lane = tid & 63;
    const int lr = lane & 15;
    const int lh = lane >> 4;
    f32x4v a0 = {0.f, 0.f, 0.f, 0.f}, a1 = {0.f, 0.f, 0.f, 0.f};
#pragma unroll
    for (int q = 0; q < 4; ++q) {
        bf16x8 a = *(const bf16x8*)&tile[lr * 136 + q * 32 + lh * 8];
        bf16x8 bb0 = *(const bf16x8*)&Wf2[(size_t)((2 * wave) * 4 + q) * 512 + lane * 8];
        bf16x8 bb1 = *(const bf16x8*)&Wf2[(size_t)((2 * wave + 1) * 4 + q) * 512 + lane * 8];
        a0 = __builtin_amdgcn_mfma_f32_16x16x32_bf16(a, bb0, a0, 0, 0, 0);
        a1 = __builtin_amdgcn_mfma_f32_16x16x32_bf16(a, bb1, a1, 0, 0, 0);
    }
    const int row0 = blockIdx.x * 16;
#pragma unroll
    for (int j = 0; j < 4; ++j) {
        const int r = row0 + lh * 4 + j;
        hb2[(size_t)r * FD + (2 * wave) * 16 + lr] = f2bf(a0[j]);
        hb2[(size_t)r * FD + (2 * wave + 1) * 16 + lr] = f2bf(a1[j]);
    }
}

// ============ gather-2: out f32 = b2 + dv^2*h2[v] + sum w*h2[src] ==============
__global__ __launch_bounds__(256) void k_agg_f32(const u16* __restrict__ hb,
                                                 const float* __restrict__ b,
                                                 const float* __restrict__ dis,
                                                 const int* __restrict__ nstart,
                                                 const int* __restrict__ ndeg,
                                                 const int* __restrict__ srcs,
                                                 float* __restrict__ out) {
    const int v = (blockIdx.x * 256 + threadIdx.x) >> 4;
    if (v >= NN) return;
    const int f8 = threadIdx.x & 15;
    const uint4* h4 = (const uint4*)hb;

    const float dv = dis[v];
    float4 aL = ((const float4*)b)[f8 * 2];
    float4 aH = ((const float4*)b)[f8 * 2 + 1];
    {
        const float sl = dv * dv;
        uint4 u = h4[(size_t)v * 16 + f8];
        acc8(aL, aH, sl, u);
    }

    int e = nstart[v];
    const int end = e + ndeg[v];
    for (; e + 3 < end; e += 4) {
        const int s0 = srcs[e], s1 = srcs[e + 1], s2 = srcs[e + 2], s3 = srcs[e + 3];
        const float w0 = dv * dis[s0];
        const float w1 = dv * dis[s1];
        const float w2 = dv * dis[s2];
        const float w3 = dv * dis[s3];
        const uint4 u0 = h4[(size_t)s0 * 16 + f8];
        const uint4 u1 = h4[(size_t)s1 * 16 + f8];
        const uint4 u2 = h4[(size_t)s2 * 16 + f8];
        const uint4 u3 = h4[(size_t)s3 * 16 + f8];
        acc8(aL, aH, w0, u0); acc8(aL, aH, w1, u1);
        acc8(aL, aH, w2, u2); acc8(aL, aH, w3, u3);
    }
    for (; e < end; ++e) {
        const int s0 = srcs[e];
        const float w0 = dv * dis[s0];
        const uint4 u0 = h4[(size_t)s0 * 16 + f8];
        acc8(aL, aH, w0, u0);
    }

    float4* o = (float4*)out;
    o[(size_t)v * 32 + f8 * 2] = aL;
    o[(size_t)v * 32 + f8 * 2 + 1] = aH;
}

// ================= launch =================

extern "C" void kernel_launch(void* const* d_in, const int* in_sizes, int n_in,
                              void* d_out, int out_size, void* d_ws, size_t ws_size,
                              hipStream_t stream) {
    const float* x  = (const float*)d_in[0];
    const int*   ei = (const int*)d_in[1];
    const float* W1 = (const float*)d_in[2];
    const float* b1 = (const float*)d_in[3];
    const float* W2 = (const float*)d_in[4];
    const float* b2 = (const float*)d_in[5];
    float* out = (float*)d_out;

    const int* row = ei;        // source (gather side)
    const int* col = ei + NE;   // target (scatter side)

    // ---- workspace layout (256B-aligned regions) ----
    char* base = (char*)d_ws;
    size_t o = 0;
    auto take = [&](size_t bytes) -> void* {
        void* p = base + o;
        o += (bytes + 255) & ~(size_t)255;
        return p;
    };
    int*   nstart  = (int*)take((size_t)NN * 4);
    int*   ndeg    = (int*)take((size_t)NN * 4);
    int*   bcur    = (int*)take(256 * 4);
    float* dis     = (float*)take((size_t)NN * 4);
    u16*   Wf1     = (u16*)take(16384 * 2);
    u16*   Wf2     = (u16*)take(16384 * 2);
    u16*   hb      = (u16*)take((size_t)NN * FD * 2);   // layer-1 GEMM out
    u16*   hb2     = (u16*)take((size_t)NN * FD * 2);   // layer-2 GEMM out
    int*   srcs    = (int*)take((size_t)NBUK * BCAP * 4);
    u32*   ebuf    = (u32*)take((size_t)NBUK * BCAP * 4);

    // 1. init cursors + pack weights
    k_init_pack<<<9, 256, 0, stream>>>(bcur, W1, W2, Wf1, Wf2);
    // 2. mega: bin edges (blocks 0..195) || GEMM-1 (blocks 196..)
    k_mega<<<NBB + GEMM_BLKS, 256, 0, stream>>>(row, col, bcur, ebuf, x, Wf1, hb);
    // 3. per-bucket counting sort -> CSC
    k_bucket<<<NBUK, 256, 0, stream>>>(ebuf, bcur, nstart, ndeg, dis, srcs);
    // 4. fused gather-1 + bias + ReLU + GEMM-2
    k_agg2<<<NGROUP, 256, 0, stream>>>(hb, b1, dis, nstart, ndeg, srcs, Wf2, hb2);
    // 5. gather-2 -> f32 out
    k_agg_f32<<<NGROUP, 256, 0, stream>>>(hb2, b2, dis, nstart, ndeg, srcs, out);
}

// Round 13
// 192.633 us; speedup vs baseline: 29.3387x; 1.0311x over previous
//
#include <hip/hip_runtime.h>

#define NN 100000
#define NE 1600000
#define FD 128
#define NBUK 196            // ceil(NN / 512), bucket = col >> 9
#define BCAP 9216           // fixed slots per bucket (mean 8163, +11 sigma)
#define EPBB 4096           // edges per block in k_bin
#define NBB 391             // ceil(NE / EPBB)
#define NGROUP 6250         // NN/16 row-groups for MFMA gemm
#define GEMM_BLKS 1563      // ceil(NGROUP / 4)

typedef unsigned int  u32;
typedef unsigned short u16;
typedef __bf16 bf16x8 __attribute__((ext_vector_type(8)));
typedef float  f32x4v __attribute__((ext_vector_type(4)));

__device__ __forceinline__ u16 f2bf(float f) {
    u32 u = __float_as_uint(f);
    u32 r = (u + 0x7FFFu + ((u >> 16) & 1u)) >> 16;   // RNE
    return (u16)r;
}

__device__ __forceinline__ void acc2(float& x, float& y, float wt, u32 w) {
    x += wt * __uint_as_float(w << 16);
    y += wt * __uint_as_float(w & 0xffff0000u);
}
__device__ __forceinline__ void acc8(float4& L, float4& H, float wt, uint4 u) {
    acc2(L.x, L.y, wt, u.x); acc2(L.z, L.w, wt, u.y);
    acc2(H.x, H.y, wt, u.z); acc2(H.z, H.w, wt, u.w);
}

// ============ init bucket cursors + pack W1/W2 into MFMA B-fragment order ======
// B elem = W[q*32 + (l>>4)*8 + j][t*16 + (l&15)]  stored at Wf[((t*4+q)*64+l)*8+j]
__global__ void k_init_pack(int* __restrict__ bcur,
                            const float* __restrict__ W1, const float* __restrict__ W2,
                            u16* __restrict__ Wf1, u16* __restrict__ Wf2) {
    if (blockIdx.x == 0) {
        if (threadIdx.x < NBUK) bcur[threadIdx.x] = threadIdx.x * BCAP;
        return;
    }
    int tid = (blockIdx.x - 1) * 256 + threadIdx.x;   // 0..2047
    if (tid >= 2048) return;
    int l = tid & 63;
    int tq = tid >> 6;
    int q = tq & 3, t = tq >> 2;
    int n = t * 16 + (l & 15);
    int k0 = q * 32 + (l >> 4) * 8;
    u32 p[4], r[4];
    for (int jj = 0; jj < 4; ++jj) {
        u16 lo1 = f2bf(W1[(size_t)(k0 + 2 * jj) * FD + n]);
        u16 hi1 = f2bf(W1[(size_t)(k0 + 2 * jj + 1) * FD + n]);
        p[jj] = (u32)lo1 | ((u32)hi1 << 16);
        u16 lo2 = f2bf(W2[(size_t)(k0 + 2 * jj) * FD + n]);
        u16 hi2 = f2bf(W2[(size_t)(k0 + 2 * jj + 1) * FD + n]);
        r[jj] = (u32)lo2 | ((u32)hi2 << 16);
    }
    *(uint4*)&Wf1[(size_t)tid * 8] = make_uint4(p[0], p[1], p[2], p[3]);
    *(uint4*)&Wf2[(size_t)tid * 8] = make_uint4(r[0], r[1], r[2], r[3]);
}

// ============ bin edges into fixed-capacity bucket regions =====================
__global__ __launch_bounds__(256) void k_bin(const int* __restrict__ row,
                                             const int* __restrict__ col,
                                             int* __restrict__ bcur,
                                             u32* __restrict__ ebuf) {
    __shared__ int hist[NBUK];
    const int tid = threadIdx.x;
    for (int i = tid; i < NBUK; i += 256) hist[i] = 0;
    __syncthreads();
    const int e0 = blockIdx.x * EPBB;
    const int e1 = min(e0 + EPBB, NE);
    for (int e = e0 + tid; e < e1; e += 256)
        atomicAdd(&hist[col[e] >> 9], 1);
    __syncthreads();
    for (int i = tid; i < NBUK; i += 256) {
        int c = hist[i];
        hist[i] = c ? atomicAdd(&bcur[i], c) : 0;
    }
    __syncthreads();
    for (int e = e0 + tid; e < e1; e += 256) {
        int c = col[e];
        int pos = atomicAdd(&hist[c >> 9], 1);
        ebuf[pos] = ((u32)row[e] << 9) | (u32)(c & 511);
    }
}

// ============ mega2: blocks [0,NBUK) bucket-sort; blocks [NBUK,..) GEMM-1 ======
__global__ __launch_bounds__(256, 4) void k_mega2(const u32* __restrict__ ebuf,
                                                  const int* __restrict__ bcur,
                                                  int* __restrict__ nstart,
                                                  int* __restrict__ ndeg,
                                                  float* __restrict__ dis,
                                                  int* __restrict__ srcs,
                                                  const float* __restrict__ x,
                                                  const u16* __restrict__ Wf1,
                                                  u16* __restrict__ hb) {
    __shared__ u16 smem[16384];     // 32 KB union: bucket uses 3 KB; gemm uses all
    const int tid = threadIdx.x;

    if (blockIdx.x < NBUK) {
        // ---- per-bucket counting sort -> CSC ----
        int* lcnt = (int*)smem;             // 512 ints
        int* s = lcnt + 512;                // 256 ints
        const int b = blockIdx.x;
        const int base = b * BCAP;
        const int end = bcur[b];            // base + actual count

        lcnt[tid] = 0; lcnt[tid + 256] = 0;
        __syncthreads();
        for (int i = base + tid; i < end; i += 256)
            atomicAdd(&lcnt[ebuf[i] & 511], 1);
        __syncthreads();

        const int c0 = lcnt[tid * 2], c1 = lcnt[tid * 2 + 1];
        s[tid] = c0 + c1;
        __syncthreads();
        for (int off = 1; off < 256; off <<= 1) {
            int t = 0;
            if (tid >= off) t = s[tid - off];
            __syncthreads();
            if (tid >= off) s[tid] += t;
            __syncthreads();
        }
        const int excl = (tid == 0) ? 0 : s[tid - 1];
        __syncthreads();
        lcnt[tid * 2] = excl;
        lcnt[tid * 2 + 1] = excl + c0;

        const int v0 = b * 512 + tid * 2;
        if (v0 < NN) {
            nstart[v0] = base + excl;
            ndeg[v0] = c0;
            dis[v0] = rsqrtf((float)c0 + 1.0f);
        }
        if (v0 + 1 < NN) {
            nstart[v0 + 1] = base + excl + c0;
            ndeg[v0 + 1] = c1;
            dis[v0 + 1] = rsqrtf((float)c1 + 1.0f);
        }
        __syncthreads();

        for (int i = base + tid; i < end; i += 256) {
            u32 p = ebuf[i];
            int pos = atomicAdd(&lcnt[p & 511], 1);
            srcs[base + pos] = (int)(p >> 9);
        }
        return;
    }

    // ---- GEMM-1: hb[r][f] = bf16( sum_k bf16(x[r][k]) * W1[k][f] ) ----
    {
        const uint4* s4 = (const uint4*)Wf1;
        uint4* d = (uint4*)smem;
#pragma unroll
        for (int i = 0; i < 8; ++i) d[tid + 256 * i] = s4[tid + 256 * i];
    }
    __syncthreads();

    const int wave = tid >> 6, lane = tid & 63;
    const int gid = (blockIdx.x - NBUK) * 4 + wave;
    if (gid >= NGROUP) return;
    const int row0 = gid * 16;
    const int lr = lane & 15;
    const int lh = lane >> 4;

    f32x4v acc[8];
#pragma unroll
    for (int t = 0; t < 8; ++t) { f32x4v z = {0.f, 0.f, 0.f, 0.f}; acc[t] = z; }

#pragma unroll
    for (int q = 0; q < 4; ++q) {
        const float* arow = x + (size_t)(row0 + lr) * FD + lh * 8 + q * 32;
        float4 f0 = *(const float4*)(arow);
        float4 f1 = *(const float4*)(arow + 4);
        union { bf16x8 v; u16 s[8]; } ua;
        ua.s[0] = f2bf(f0.x); ua.s[1] = f2bf(f0.y);
        ua.s[2] = f2bf(f0.z); ua.s[3] = f2bf(f0.w);
        ua.s[4] = f2bf(f1.x); ua.s[5] = f2bf(f1.y);
        ua.s[6] = f2bf(f1.z); ua.s[7] = f2bf(f1.w);
        bf16x8 a = ua.v;
#pragma unroll
        for (int t = 0; t < 8; ++t) {
            bf16x8 bfr = *(const bf16x8*)(&smem[(size_t)(t * 4 + q) * 512 + lane * 8]);
            acc[t] = __builtin_amdgcn_mfma_f32_16x16x32_bf16(a, bfr, acc[t], 0, 0, 0);
        }
    }
#pragma unroll
    for (int t = 0; t < 8; ++t) {
#pragma unroll
        for (int j = 0; j < 4; ++j) {
            const int r = row0 + lh * 4 + j;
            hb[(size_t)r * FD + t * 16 + lr] = f2bf(acc[t][j]);
        }
    }
}

// ============ fused: gather-1 + bias + ReLU + GEMM-2 -> hb2 (bf16) =============
__global__ __launch_bounds__(256) void k_agg2(const u16* __restrict__ hb,
                                              const float* __restrict__ b1,
                                              const float* __restrict__ dis,
                                              const int* __restrict__ nstart,
                                              const int* __restrict__ ndeg,
                                              const int* __restrict__ srcs,
                                              const u16* __restrict__ Wf2,
                                              u16* __restrict__ hb2) {
    __shared__ u16 tile[16 * 136];      // 4352 B
    const int tid = threadIdx.x;
    const int nl = tid >> 4;            // node-local 0..15
    const int f8 = tid & 15;            // 8-feature slice
    const int v = blockIdx.x * 16 + nl; // always < NN (6250*16 = NN)
    const uint4* h4 = (const uint4*)hb;

    const float dv = dis[v];
    float4 aL = ((const float4*)b1)[f8 * 2];
    float4 aH = ((const float4*)b1)[f8 * 2 + 1];
    {
        const float sl = dv * dv;
        uint4 u = h4[(size_t)v * 16 + f8];
        acc8(aL, aH, sl, u);
    }

    int e = nstart[v];
    const int end = e + ndeg[v];
    for (; e + 3 < end; e += 4) {
        const int s0 = srcs[e], s1 = srcs[e + 1], s2 = srcs[e + 2], s3 = srcs[e + 3];
        const float w0 = dv * dis[s0];
        const float w1 = dv * dis[s1];
        const float w2 = dv * dis[s2];
        const float w3 = dv * dis[s3];
        const uint4 u0 = h4[(size_t)s0 * 16 + f8];
        const uint4 u1 = h4[(size_t)s1 * 16 + f8];
        const uint4 u2 = h4[(size_t)s2 * 16 + f8];
        const uint4 u3 = h4[(size_t)s3 * 16 + f8];
        acc8(aL, aH, w0, u0); acc8(aL, aH, w1, u1);
        acc8(aL, aH, w2, u2); acc8(aL, aH, w3, u3);
    }
    for (; e < end; ++e) {
        const int s0 = srcs[e];
        const float w0 = dv * dis[s0];
        const uint4 u0 = h4[(size_t)s0 * 16 + f8];
        acc8(aL, aH, w0, u0);
    }

    // ReLU + bf16 pack -> LDS tile
    {
        uint4 p;
        p.x = (u32)f2bf(fmaxf(aL.x, 0.f)) | ((u32)f2bf(fmaxf(aL.y, 0.f)) << 16);
        p.y = (u32)f2bf(fmaxf(aL.z, 0.f)) | ((u32)f2bf(fmaxf(aL.w, 0.f)) << 16);
        p.z = (u32)f2bf(fmaxf(aH.x, 0.f)) | ((u32)f2bf(fmaxf(aH.y, 0.f)) << 16);
        p.w = (u32)f2bf(fmaxf(aH.z, 0.f)) | ((u32)f2bf(fmaxf(aH.w, 0.f)) << 16);
        *(uint4*)&tile[nl * 136 + f8 * 8] = p;
    }
    __syncthreads();

    // GEMM-2 on the 16-row tile: wave w owns n-tiles 2w, 2w+1
    const int wave = tid >> 6, lane = tid & 63;
    const int lr = lane & 15;
    const int lh = lane >> 4;
    f32x4v a0 = {0.f, 0.f, 0.f, 0.f}, a1 = {0.f, 0.f, 0.f, 0.f};
#pragma unroll
    for (int q = 0; q < 4; ++q) {
        bf16x8 a = *(const bf16x8*)&tile[lr * 136 + q * 32 + lh * 8];
        bf16x8 bb0 = *(const bf16x8*)&Wf2[(size_t)((2 * wave) * 4 + q) * 512 + lane * 8];
        bf16x8 bb1 = *(const bf16x8*)&Wf2[(size_t)((2 * wave + 1) * 4 + q) * 512 + lane * 8];
        a0 = __builtin_amdgcn_mfma_f32_16x16x32_bf16(a, bb0, a0, 0, 0, 0);
        a1 = __builtin_amdgcn_mfma_f32_16x16x32_bf16(a, bb1, a1, 0, 0, 0);
    }
    const int row0 = blockIdx.x * 16;
#pragma unroll
    for (int j = 0; j < 4; ++j) {
        const int r = row0 + lh * 4 + j;
        hb2[(size_t)r * FD + (2 * wave) * 16 + lr] = f2bf(a0[j]);
        hb2[(size_t)r * FD + (2 * wave + 1) * 16 + lr] = f2bf(a1[j]);
    }
}

// ============ gather-2: out f32 = b2 + dv^2*h2[v] + sum w*h2[src] ==============
__global__ __launch_bounds__(256) void k_agg_f32(const u16* __restrict__ hb,
                                                 const float* __restrict__ b,
                                                 const float* __restrict__ dis,
                                                 const int* __restrict__ nstart,
                                                 const int* __restrict__ ndeg,
                                                 const int* __restrict__ srcs,
                                                 float* __restrict__ out) {
    const int v = (blockIdx.x * 256 + threadIdx.x) >> 4;
    if (v >= NN) return;
    const int f8 = threadIdx.x & 15;
    const uint4* h4 = (const uint4*)hb;

    const float dv = dis[v];
    float4 aL = ((const float4*)b)[f8 * 2];
    float4 aH = ((const float4*)b)[f8 * 2 + 1];
    {
        const float sl = dv * dv;
        uint4 u = h4[(size_t)v * 16 + f8];
        acc8(aL, aH, sl, u);
    }

    int e = nstart[v];
    const int end = e + ndeg[v];
    for (; e + 3 < end; e += 4) {
        const int s0 = srcs[e], s1 = srcs[e + 1], s2 = srcs[e + 2], s3 = srcs[e + 3];
        const float w0 = dv * dis[s0];
        const float w1 = dv * dis[s1];
        const float w2 = dv * dis[s2];
        const float w3 = dv * dis[s3];
        const uint4 u0 = h4[(size_t)s0 * 16 + f8];
        const uint4 u1 = h4[(size_t)s1 * 16 + f8];
        const uint4 u2 = h4[(size_t)s2 * 16 + f8];
        const uint4 u3 = h4[(size_t)s3 * 16 + f8];
        acc8(aL, aH, w0, u0); acc8(aL, aH, w1, u1);
        acc8(aL, aH, w2, u2); acc8(aL, aH, w3, u3);
    }
    for (; e < end; ++e) {
        const int s0 = srcs[e];
        const float w0 = dv * dis[s0];
        const uint4 u0 = h4[(size_t)s0 * 16 + f8];
        acc8(aL, aH, w0, u0);
    }

    // nontemporal final stores (out is never re-read on device)
    f32x4v vL = {aL.x, aL.y, aL.z, aL.w};
    f32x4v vH = {aH.x, aH.y, aH.z, aH.w};
    f32x4v* o = (f32x4v*)out;
    __builtin_nontemporal_store(vL, &o[(size_t)v * 32 + f8 * 2]);
    __builtin_nontemporal_store(vH, &o[(size_t)v * 32 + f8 * 2 + 1]);
}

// ================= launch =================

extern "C" void kernel_launch(void* const* d_in, const int* in_sizes, int n_in,
                              void* d_out, int out_size, void* d_ws, size_t ws_size,
                              hipStream_t stream) {
    const float* x  = (const float*)d_in[0];
    const int*   ei = (const int*)d_in[1];
    const float* W1 = (const float*)d_in[2];
    const float* b1 = (const float*)d_in[3];
    const float* W2 = (const float*)d_in[4];
    const float* b2 = (const float*)d_in[5];
    float* out = (float*)d_out;

    const int* row = ei;        // source (gather side)
    const int* col = ei + NE;   // target (scatter side)

    // ---- workspace layout (256B-aligned regions) ----
    char* base = (char*)d_ws;
    size_t o = 0;
    auto take = [&](size_t bytes) -> void* {
        void* p = base + o;
        o += (bytes + 255) & ~(size_t)255;
        return p;
    };
    int*   nstart  = (int*)take((size_t)NN * 4);
    int*   ndeg    = (int*)take((size_t)NN * 4);
    int*   bcur    = (int*)take(256 * 4);
    float* dis     = (float*)take((size_t)NN * 4);
    u16*   Wf1     = (u16*)take(16384 * 2);
    u16*   Wf2     = (u16*)take(16384 * 2);
    u16*   hb      = (u16*)take((size_t)NN * FD * 2);   // layer-1 GEMM out
    u16*   hb2     = (u16*)take((size_t)NN * FD * 2);   // layer-2 GEMM out
    int*   srcs    = (int*)take((size_t)NBUK * BCAP * 4);
    u32*   ebuf    = (u32*)take((size_t)NBUK * BCAP * 4);

    // 1. init cursors + pack weights
    k_init_pack<<<9, 256, 0, stream>>>(bcur, W1, W2, Wf1, Wf2);
    // 2. bin edges (391 blocks, fills the machine)
    k_bin<<<NBB, 256, 0, stream>>>(row, col, bcur, ebuf);
    // 3. mega2: bucket sort (blocks 0..195) || GEMM-1 (blocks 196..)
    k_mega2<<<NBUK + GEMM_BLKS, 256, 0, stream>>>(ebuf, bcur, nstart, ndeg, dis, srcs,
                                                  x, Wf1, hb);
    // 4. fused gather-1 + bias + ReLU + GEMM-2
    k_agg2<<<NGROUP, 256, 0, stream>>>(hb, b1, dis, nstart, ndeg, srcs, Wf2, hb2);
    // 5. gather-2 -> f32 out
    k_agg_f32<<<NGROUP, 256, 0, stream>>>(hb2, b2, dis, nstart, ndeg, srcs, out);
}